// Round 11
// baseline (405.871 us; speedup 1.0000x reference)
//
#include <hip/hip_runtime.h>
#include <cstdint>
#include <cstddef>

#define NN 50000
#define NE 800000
#define FN 128
#define FE 32
#define HD 64
#define SCAN_NB ((NN + 255) / 256)   // 196

__device__ __forceinline__ float lrelu(float x) { return x > 0.f ? x : 0.2f * x; }

// order-preserving float<->uint map for atomicMax on floats (0 == -inf sentinel)
__device__ __forceinline__ unsigned omap(float f) {
  unsigned u = __float_as_uint(f);
  return (u & 0x80000000u) ? ~u : (u | 0x80000000u);
}
__device__ __forceinline__ float odec(unsigned u) {
  return __uint_as_float((u & 0x80000000u) ? (u ^ 0x80000000u) : ~u);
}

// small[] layout (floats): 0..63 vec1 | 64..127 vec2 | 128..159 p1 | 160..191 p2
// 192 c1 | 193 c2 | 194 a_self1 | 195 a_self2 | 228 sum_d1 | 229 sum_d2
// maxi[] (uint): 0 Mas1 | 1 Mas2 | 2 Mae1 | 3 Mae2
__global__ void k_small0(const float* __restrict__ le1W, const float* __restrict__ ae1,
                         const float* __restrict__ le2W, const float* __restrict__ ae2,
                         const float* __restrict__ encW, const float* __restrict__ encb,
                         const float* __restrict__ s1W,
                         float* __restrict__ small, float* __restrict__ Scomb) {
  __shared__ float sv1[64], sv2[64];
  int t = threadIdx.x;  // 64 threads = 1 wave
  float v1 = 0.f, v2 = 0.f;
  for (int j = 0; j < 64; ++j) {
    v1 += le1W[j * 64 + t] * ae1[j];
    v2 += le2W[j * 64 + t] * ae2[j];
  }
  sv1[t] = v1; sv2[t] = v2;
  small[t] = v1; small[64 + t] = v2;
  float cb1 = encb[t] * v1, cb2 = encb[t] * v2;
  #pragma unroll
  for (int m = 32; m; m >>= 1) { cb1 += __shfl_xor(cb1, m); cb2 += __shfl_xor(cb2, m); }
  __syncthreads();
  if (t < 32) {
    float p1 = 0.f, p2 = 0.f;
    for (int i = 0; i < 64; ++i) {
      p1 += encW[i * 32 + t] * sv1[i];
      p2 += encW[i * 32 + t] * sv2[i];
    }
    small[128 + t] = p1; small[160 + t] = p2;
  }
  if (t == 0) { small[192] = cb1; small[193] = cb2; }
  // Scomb[128][64]: rows 0..63 = s1_W[:, :64]; rows 64..127 = s1_W[:, 64:]
  for (int j = 0; j < 64; ++j) {
    Scomb[j * 64 + t] = s1W[j * 128 + t];
    Scomb[(64 + j) * 64 + t] = s1W[j * 128 + 64 + t];
  }
}

// hierarchical exclusive scan of counts -> offa, offa[NN]=NE
__global__ __launch_bounds__(256) void k_scanA(const int* __restrict__ counts,
                                               int* __restrict__ loc, int* __restrict__ blocksums) {
  int tid = threadIdx.x;
  int i = blockIdx.x * 256 + tid;
  int v = (i < NN) ? counts[i] : 0;
  int lane = tid & 63, wid = tid >> 6;
  int x = v;
  #pragma unroll
  for (int d = 1; d < 64; d <<= 1) {
    int y = __shfl_up(x, d);
    if (lane >= d) x += y;
  }
  __shared__ int ws[4], wpref[4];
  if (lane == 63) ws[wid] = x;
  __syncthreads();
  if (tid == 0) {
    int run = 0;
    #pragma unroll
    for (int w = 0; w < 4; ++w) { wpref[w] = run; run += ws[w]; }
    blocksums[blockIdx.x] = run;
  }
  __syncthreads();
  if (i < NN) loc[i] = x - v + wpref[wid];
}

// also finalizes the self-loop scalars
__global__ __launch_bounds__(256) void k_scanB(int* __restrict__ blocksums, int* __restrict__ offa,
                                               float* __restrict__ small) {
  int tid = threadIdx.x;
  int v = (tid < SCAN_NB) ? blocksums[tid] : 0;
  int lane = tid & 63, wid = tid >> 6;
  int x = v;
  #pragma unroll
  for (int d = 1; d < 64; d <<= 1) {
    int y = __shfl_up(x, d);
    if (lane >= d) x += y;
  }
  __shared__ int ws[4], wpref[4];
  if (lane == 63) ws[wid] = x;
  __syncthreads();
  if (tid == 0) {
    int run = 0;
    #pragma unroll
    for (int w = 0; w < 4; ++w) { wpref[w] = run; run += ws[w]; }
    offa[NN] = run;   // == NE
    small[194] = small[228] * (1.0f / NE);
    small[195] = small[229] * (1.0f / NE);
  }
  __syncthreads();
  if (tid < SCAN_NB) blocksums[tid] = x - v + wpref[wid];
}

__global__ __launch_bounds__(256) void k_scanC(int* __restrict__ offa, const int* __restrict__ blocksums) {
  int i = blockIdx.x * 256 + threadIdx.x;
  if (i < NN) offa[i] = offa[i] + blocksums[blockIdx.x];
}

// LDS-staged streaming pass: 128-thread blocks (16.9KB LDS -> ~9 blocks/CU) for occupancy.
// emits a_e1,a_e2,rank (coalesced), counts (atomic ret=rank), d-sums + d-maxes.
__global__ __launch_bounds__(128) void k_edgepre(const float* __restrict__ attr,
                                                 const int* __restrict__ col,
                                                 const float* __restrict__ small,
                                                 float* __restrict__ a_e1, float* __restrict__ a_e2,
                                                 int* __restrict__ rank,
                                                 int* __restrict__ counts,
                                                 float* __restrict__ sums,
                                                 unsigned* __restrict__ maxi) {
  __shared__ float sattr[128 * 33];
  __shared__ float redbuf[8];
  int tid = threadIdx.x;
  float sp1[32], sp2[32];
  #pragma unroll
  for (int j = 0; j < 8; ++j) {
    float4 v1 = ((const float4*)(small + 128))[j];
    float4 v2 = ((const float4*)(small + 160))[j];
    sp1[j*4+0] = v1.x; sp1[j*4+1] = v1.y; sp1[j*4+2] = v1.z; sp1[j*4+3] = v1.w;
    sp2[j*4+0] = v2.x; sp2[j*4+1] = v2.y; sp2[j*4+2] = v2.z; sp2[j*4+3] = v2.w;
  }
  float c1 = small[192], c2 = small[193];
  int e = blockIdx.x * 128 + tid;
  int c = col[e];   // issue early: independent of the staging loop
  const float4* ain = (const float4*)(attr + (size_t)blockIdx.x * 128 * FE);
  #pragma unroll
  for (int it = 0; it < 8; ++it) {
    int idx = it * 128 + tid;          // float4 index in tile (1024 total)
    float4 v = ain[idx];
    int r = idx >> 3, ch = idx & 7;
    float* dst = &sattr[r * 33 + ch * 4];
    dst[0] = v.x; dst[1] = v.y; dst[2] = v.z; dst[3] = v.w;
  }
  __syncthreads();
  const float* myrow = &sattr[tid * 33];
  float d1 = c1, d2 = c2;
  #pragma unroll
  for (int j = 0; j < 32; ++j) {
    float a = myrow[j];
    d1 += a * sp1[j];
    d2 += a * sp2[j];
  }
  a_e1[e] = d1;
  a_e2[e] = d2;
  rank[e] = atomicAdd(&counts[c], 1);
  // block reduce: sums (for self-loop mean) and maxes (for softmax bound)
  float s1 = d1, s2 = d2, m1 = d1, m2 = d2;
  #pragma unroll
  for (int m = 32; m; m >>= 1) {
    s1 += __shfl_xor(s1, m); s2 += __shfl_xor(s2, m);
    m1 = fmaxf(m1, __shfl_xor(m1, m)); m2 = fmaxf(m2, __shfl_xor(m2, m));
  }
  int wid = tid >> 6;   // 0..1
  if ((tid & 63) == 0) { redbuf[wid] = s1; redbuf[2 + wid] = s2; redbuf[4 + wid] = m1; redbuf[6 + wid] = m2; }
  __syncthreads();
  if (tid == 0) atomicAdd(&sums[0], redbuf[0] + redbuf[1]);
  if (tid == 1) atomicAdd(&sums[1], redbuf[2] + redbuf[3]);
  if (tid == 2) atomicMax(&maxi[2], omap(fmaxf(redbuf[4], redbuf[5])));
  if (tid == 3) atomicMax(&maxi[3], omap(fmaxf(redbuf[6], redbuf[7])));
}

// atomic-free scatter, 2 independent edge-chains per thread (MLP), guarded tail
__global__ __launch_bounds__(256) void k_scatter(const int* __restrict__ row, const int* __restrict__ col,
                                                 const float* __restrict__ a_e1, const float* __restrict__ a_e2,
                                                 const int* __restrict__ rank, const int* __restrict__ offa,
                                                 int4* __restrict__ pk) {
  int t = blockIdx.x * 256 + threadIdx.x;
  if (t >= NE / 2) return;
  int e0 = t, e1 = t + NE / 2;
  int c0 = col[e0], c1 = col[e1];
  int r0 = rank[e0], r1 = rank[e1];
  int o0 = offa[c0], o1 = offa[c1];
  int4 q0, q1;
  q0.x = row[e0]; q0.y = __float_as_int(a_e1[e0]); q0.z = __float_as_int(a_e2[e0]); q0.w = 0;
  q1.x = row[e1]; q1.y = __float_as_int(a_e1[e1]); q1.z = __float_as_int(a_e2[e1]); q1.w = 0;
  pk[o0 + r0] = q0;
  pk[o1 + r1] = q1;
}

// C[M][ldc-tile] = A[M][K] * B^T, B is [64][K] row-major (per blockIdx.y tile)
// ASD: also emit asrc/adst from the accumulator tile + global max(asrc) -> maxslot
template <int K, int ASD>
__global__ __launch_bounds__(256) void k_gemm(const float* __restrict__ A, const float* __restrict__ B,
                                              float* __restrict__ C, int M, int ldc,
                                              const float* __restrict__ as, const float* __restrict__ ad,
                                              float* __restrict__ asrc, float* __restrict__ adst,
                                              unsigned* __restrict__ maxslot) {
  __shared__ float At[64][68];
  __shared__ float Bt[64][68];
  int tid = threadIdx.x;
  int m0 = blockIdx.x * 64;
  const float* Bp = B + (size_t)blockIdx.y * 64 * K;
  float acc[4][4] = {};
  for (int kc = 0; kc < K; kc += 64) {
    #pragma unroll
    for (int it = 0; it < 4; ++it) {
      int idx = it * 256 + tid;
      int m = idx & 63, kv = idx >> 6;  // kv in 0..15
      float4 bv = ((const float4*)(Bp + (size_t)m * K + kc))[kv];
      Bt[kv*4+0][m] = bv.x; Bt[kv*4+1][m] = bv.y; Bt[kv*4+2][m] = bv.z; Bt[kv*4+3][m] = bv.w;
      int gm = m0 + m;
      float4 av = make_float4(0.f, 0.f, 0.f, 0.f);
      if (gm < M) av = ((const float4*)(A + (size_t)gm * K + kc))[kv];
      At[kv*4+0][m] = av.x; At[kv*4+1][m] = av.y; At[kv*4+2][m] = av.z; At[kv*4+3][m] = av.w;
    }
    __syncthreads();
    int tn = tid & 15, tm = tid >> 4;
    #pragma unroll 8
    for (int k = 0; k < 64; ++k) {
      float4 a4 = *(const float4*)&At[k][tm * 4];
      float4 b4 = *(const float4*)&Bt[k][tn * 4];
      acc[0][0] += a4.x*b4.x; acc[0][1] += a4.x*b4.y; acc[0][2] += a4.x*b4.z; acc[0][3] += a4.x*b4.w;
      acc[1][0] += a4.y*b4.x; acc[1][1] += a4.y*b4.y; acc[1][2] += a4.y*b4.z; acc[1][3] += a4.y*b4.w;
      acc[2][0] += a4.z*b4.x; acc[2][1] += a4.z*b4.y; acc[2][2] += a4.z*b4.z; acc[2][3] += a4.z*b4.w;
      acc[3][0] += a4.w*b4.x; acc[3][1] += a4.w*b4.y; acc[3][2] += a4.w*b4.z; acc[3][3] += a4.w*b4.w;
    }
    __syncthreads();
  }
  int tn = tid & 15, tm = tid >> 4;
  #pragma unroll
  for (int i = 0; i < 4; ++i) {
    int gm = m0 + tm * 4 + i;
    if (gm < M) {
      float4 o = make_float4(acc[i][0], acc[i][1], acc[i][2], acc[i][3]);
      *(float4*)(C + (size_t)gm * ldc + blockIdx.y * 64 + tn * 4) = o;
    }
  }
  if constexpr (ASD) {
    __shared__ float wmax[4];
    float4 asv = ((const float4*)as)[tn];
    float4 adv = ((const float4*)ad)[tn];
    float smax = -1e30f;
    #pragma unroll
    for (int i = 0; i < 4; ++i) {
      float s = acc[i][0]*asv.x + acc[i][1]*asv.y + acc[i][2]*asv.z + acc[i][3]*asv.w;
      float d = acc[i][0]*adv.x + acc[i][1]*adv.y + acc[i][2]*adv.z + acc[i][3]*adv.w;
      #pragma unroll
      for (int m = 8; m; m >>= 1) { s += __shfl_xor(s, m, 16); d += __shfl_xor(d, m, 16); }
      int gm = m0 + tm * 4 + i;
      if (tn == 0 && gm < M) { asrc[gm] = s; adst[gm] = d; smax = fmaxf(smax, s); }
    }
    #pragma unroll
    for (int m = 32; m; m >>= 1) smax = fmaxf(smax, __shfl_xor(smax, m));
    if ((tid & 63) == 0) wmax[tid >> 6] = smax;
    __syncthreads();
    if (tid == 0)
      atomicMax(maxslot, omap(fmaxf(fmaxf(wmax[0], wmax[1]), fmaxf(wmax[2], wmax[3]))));
  }
}

// one wave per destination node, SINGLE PASS softmax (global-bound shift),
// 4-way unrolled gather loop with independent accumulators (ILP for load latency).
__global__ __launch_bounds__(256) void k_agg(const float* __restrict__ h, const int* __restrict__ offa,
                                             const int4* __restrict__ pk, int comp,
                                             const float* __restrict__ asrc, const float* __restrict__ adst,
                                             const float* __restrict__ small, int selfIdx,
                                             const unsigned* __restrict__ maxi,
                                             const float* __restrict__ bias, float* __restrict__ outp,
                                             int do_relu) {
  int gt = blockIdx.x * 256 + threadIdx.x;
  int n = gt >> 6, lane = gt & 63;
  if (n >= NN) return;
  int beg = offa[n], end = offa[n + 1];
  float adn = adst[n];
  // shift bound: m >= every alpha in this segment (softmax is shift-invariant)
  float mx = lrelu(odec(maxi[comp]) + adn + odec(maxi[2 + comp]));
  float alpha_self = lrelu(asrc[n] + adn + small[selfIdx]);
  float ex_self = __expf(alpha_self - mx);
  float denom = ex_self;
  float acc0 = ex_self * h[(size_t)n * 64 + lane];
  float acc1 = 0.f, acc2 = 0.f, acc3 = 0.f;
  for (int base = beg; base < end; base += 64) {
    int p = base + lane;
    int cnt = min(64, end - base);
    float ex = 0.f; int s = 0;
    if (p < end) {
      int4 q = pk[p];
      s = q.x;
      float ae = __int_as_float(comp ? q.z : q.y);
      ex = __expf(lrelu(asrc[s] + adn + ae) - mx);
    }
    float exs = ex;
    #pragma unroll
    for (int m = 32; m; m >>= 1) exs += __shfl_xor(exs, m);
    denom += exs;
    int q4 = cnt & ~3;
    for (int q = 0; q < q4; q += 4) {
      float e0 = __shfl(ex, q),     e1 = __shfl(ex, q + 1);
      float e2 = __shfl(ex, q + 2), e3 = __shfl(ex, q + 3);
      int s0 = __shfl(s, q),     s1 = __shfl(s, q + 1);
      int s2 = __shfl(s, q + 2), s3 = __shfl(s, q + 3);
      acc0 += e0 * h[(size_t)s0 * 64 + lane];
      acc1 += e1 * h[(size_t)s1 * 64 + lane];
      acc2 += e2 * h[(size_t)s2 * 64 + lane];
      acc3 += e3 * h[(size_t)s3 * 64 + lane];
    }
    for (int q = q4; q < cnt; ++q) {
      float eq = __shfl(ex, q);
      int sq = __shfl(s, q);
      acc0 += eq * h[(size_t)sq * 64 + lane];
    }
  }
  float r = (acc0 + acc1 + acc2 + acc3) / denom + bias[lane];
  if (do_relu) r = fmaxf(r, 0.f);
  outp[(size_t)n * 64 + lane] = r;
}

// edge scorer: 16 lanes per edge
__global__ __launch_bounds__(256) void k_final(const int* __restrict__ row, const int* __restrict__ col,
                                               const float* __restrict__ uv, const float* __restrict__ s1b,
                                               const float* __restrict__ s2w, const float* __restrict__ s2b,
                                               float* __restrict__ outp) {
  int gt = blockIdx.x * 256 + threadIdx.x;
  int e = gt >> 4, i = gt & 15;
  if (e >= NE) return;
  int r = row[e], c = col[e];
  float4 a = ((const float4*)(uv + (size_t)r * 128))[i];
  float4 b = ((const float4*)(uv + (size_t)c * 128 + 64))[i];
  float4 bb = ((const float4*)s1b)[i];
  float4 ww = ((const float4*)s2w)[i];
  float z = fmaxf(a.x + b.x + bb.x, 0.f) * ww.x
          + fmaxf(a.y + b.y + bb.y, 0.f) * ww.y
          + fmaxf(a.z + b.z + bb.z, 0.f) * ww.z
          + fmaxf(a.w + b.w + bb.w, 0.f) * ww.w;
  #pragma unroll
  for (int m = 1; m < 16; m <<= 1) z += __shfl_xor(z, m, 16);
  if (i == 0) outp[e] = 1.f / (1.f + __expf(-(z + s2b[0])));
}

extern "C" void kernel_launch(void* const* d_in, const int* in_sizes, int n_in,
                              void* d_out, int out_size, void* d_ws, size_t ws_size,
                              hipStream_t stream) {
  const float* x    = (const float*)d_in[0];
  const float* attr = (const float*)d_in[1];
  const int*   eidx = (const int*)d_in[2];   // [2][NE]: row then col
  const float* encW = (const float*)d_in[3];
  const float* encb = (const float*)d_in[4];
  const float* W1   = (const float*)d_in[5];
  const float* le1W = (const float*)d_in[6];
  const float* as1  = (const float*)d_in[7];
  const float* ad1  = (const float*)d_in[8];
  const float* ae1w = (const float*)d_in[9];
  const float* b1   = (const float*)d_in[10];
  const float* W2   = (const float*)d_in[11];
  const float* le2W = (const float*)d_in[12];
  const float* as2  = (const float*)d_in[13];
  const float* ad2  = (const float*)d_in[14];
  const float* ae2w = (const float*)d_in[15];
  const float* b2   = (const float*)d_in[16];
  const float* s1W  = (const float*)d_in[17];
  const float* s1b  = (const float*)d_in[18];
  const float* s2w  = (const float*)d_in[19];
  const float* s2b  = (const float*)d_in[20];
  float* outp = (float*)d_out;

  const int* row = eidx;
  const int* col = eidx + NE;

  char* p = (char*)d_ws;
  auto alloc = [&](size_t bytes) { char* r = p; p += (bytes + 255) & ~(size_t)255; return r; };
  float* small = (float*)alloc(1024);
  unsigned* maxi = (unsigned*)alloc(256);
  float* Scomb = (float*)alloc(8192 * 4);
  int*   counts= (int*)alloc((size_t)NN * 4);
  int*   offa  = (int*)alloc((size_t)(NN + 1) * 4);
  int*   bsums = (int*)alloc((size_t)SCAN_NB * 4);
  float* a_e1  = (float*)alloc((size_t)NE * 4);
  float* a_e2  = (float*)alloc((size_t)NE * 4);
  int*   rank  = (int*)alloc((size_t)NE * 4);
  int4*  pk    = (int4*)alloc((size_t)NE * 16);
  float* h1    = (float*)alloc((size_t)NN * 64 * 4);
  float* out1  = (float*)alloc((size_t)NN * 64 * 4);   // contiguous after h1
  float* h2    = (float*)alloc((size_t)NN * 64 * 4);
  float* out2  = (float*)alloc((size_t)NN * 64 * 4);
  float* asrc1 = (float*)alloc((size_t)NN * 4);
  float* adst1 = (float*)alloc((size_t)NN * 4);
  float* asrc2 = (float*)alloc((size_t)NN * 4);
  float* adst2 = (float*)alloc((size_t)NN * 4);
  float* uv = h1;  // [NN][128], reuses h1||out1 (both dead by then)

  hipMemsetAsync(small, 0, 1024, stream);
  hipMemsetAsync(maxi, 0, 256, stream);
  hipMemsetAsync(counts, 0, (size_t)NN * 4, stream);

  k_small0<<<1, 64, 0, stream>>>(le1W, ae1w, le2W, ae2w, encW, encb, s1W, small, Scomb);
  k_edgepre<<<NE / 128, 128, 0, stream>>>(attr, col, small, a_e1, a_e2, rank, counts, small + 228, maxi);
  k_scanA<<<SCAN_NB, 256, 0, stream>>>(counts, offa, bsums);
  k_scanB<<<1, 256, 0, stream>>>(bsums, offa, small);
  k_scanC<<<SCAN_NB, 256, 0, stream>>>(offa, bsums);
  k_scatter<<<(NE / 2 + 255) / 256, 256, 0, stream>>>(row, col, a_e1, a_e2, rank, offa, pk);

  // layer 1
  k_gemm<128, 1><<<dim3((NN + 63) / 64, 1), 256, 0, stream>>>(x, W1, h1, NN, 64, as1, ad1, asrc1, adst1, maxi + 0);
  k_agg<<<(NN * 64) / 256, 256, 0, stream>>>(h1, offa, pk, 0, asrc1, adst1,
                                             small, 194, maxi, b1, out1, 1);
  // layer 2
  k_gemm<64, 1><<<dim3((NN + 63) / 64, 1), 256, 0, stream>>>(out1, W2, h2, NN, 64, as2, ad2, asrc2, adst2, maxi + 1);
  k_agg<<<(NN * 64) / 256, 256, 0, stream>>>(h2, offa, pk, 1, asrc2, adst2,
                                             small, 195, maxi, b2, out2, 0);
  // scorer: uv = [u | v]
  k_gemm<64, 0><<<dim3((NN + 63) / 64, 2), 256, 0, stream>>>(out2, Scomb, uv, NN, 128, nullptr, nullptr, nullptr, nullptr, nullptr);
  k_final<<<(NE * 16) / 256, 256, 0, stream>>>(row, col, uv, s1b, s2w, s2b, outp);
}

// Round 12
// 318.651 us; speedup vs baseline: 1.2737x; 1.2737x over previous
//
#include <hip/hip_runtime.h>
#include <cstdint>
#include <cstddef>

#define NN 50000
#define NE 800000
#define FN 128
#define FE 32
#define HD 64
#define SCAN_NB ((NN + 255) / 256)   // 196
#define EP_NB (NE / 256)             // 3125 edgepre blocks
#define GM_NB ((NN + 63) / 64)       // 782 gemm blocks

__device__ __forceinline__ float lrelu(float x) { return x > 0.f ? x : 0.2f * x; }

// order-preserving float<->uint map for atomicMax on floats (0 == -inf sentinel)
__device__ __forceinline__ unsigned omap(float f) {
  unsigned u = __float_as_uint(f);
  return (u & 0x80000000u) ? ~u : (u | 0x80000000u);
}
__device__ __forceinline__ float odec(unsigned u) {
  return __uint_as_float((u & 0x80000000u) ? (u ^ 0x80000000u) : ~u);
}

// small[] layout (floats): 0..63 vec1 | 64..127 vec2 | 128..159 p1 | 160..191 p2
// 192 c1 | 193 c2 | 194 a_self1 | 195 a_self2 | 228 sum_d1 | 229 sum_d2
// maxi[] (uint): 0 Mas1 | 1 Mas2 | 2 Mae1 | 3 Mae2
__global__ void k_small0(const float* __restrict__ le1W, const float* __restrict__ ae1,
                         const float* __restrict__ le2W, const float* __restrict__ ae2,
                         const float* __restrict__ encW, const float* __restrict__ encb,
                         const float* __restrict__ s1W,
                         float* __restrict__ small, float* __restrict__ Scomb) {
  __shared__ float sv1[64], sv2[64];
  int t = threadIdx.x;  // 64 threads = 1 wave
  float v1 = 0.f, v2 = 0.f;
  for (int j = 0; j < 64; ++j) {
    v1 += le1W[j * 64 + t] * ae1[j];
    v2 += le2W[j * 64 + t] * ae2[j];
  }
  sv1[t] = v1; sv2[t] = v2;
  small[t] = v1; small[64 + t] = v2;
  float cb1 = encb[t] * v1, cb2 = encb[t] * v2;
  #pragma unroll
  for (int m = 32; m; m >>= 1) { cb1 += __shfl_xor(cb1, m); cb2 += __shfl_xor(cb2, m); }
  __syncthreads();
  if (t < 32) {
    float p1 = 0.f, p2 = 0.f;
    for (int i = 0; i < 64; ++i) {
      p1 += encW[i * 32 + t] * sv1[i];
      p2 += encW[i * 32 + t] * sv2[i];
    }
    small[128 + t] = p1; small[160 + t] = p2;
  }
  if (t == 0) { small[192] = cb1; small[193] = cb2; }
  // Scomb[128][64]: rows 0..63 = s1_W[:, :64]; rows 64..127 = s1_W[:, 64:]
  for (int j = 0; j < 64; ++j) {
    Scomb[j * 64 + t] = s1W[j * 128 + t];
    Scomb[(64 + j) * 64 + t] = s1W[j * 128 + 64 + t];
  }
}

// hierarchical exclusive scan of counts -> offa, offa[NN]=NE
__global__ __launch_bounds__(256) void k_scanA(const int* __restrict__ counts,
                                               int* __restrict__ loc, int* __restrict__ blocksums) {
  int tid = threadIdx.x;
  int i = blockIdx.x * 256 + tid;
  int v = (i < NN) ? counts[i] : 0;
  int lane = tid & 63, wid = tid >> 6;
  int x = v;
  #pragma unroll
  for (int d = 1; d < 64; d <<= 1) {
    int y = __shfl_up(x, d);
    if (lane >= d) x += y;
  }
  __shared__ int ws[4], wpref[4];
  if (lane == 63) ws[wid] = x;
  __syncthreads();
  if (tid == 0) {
    int run = 0;
    #pragma unroll
    for (int w = 0; w < 4; ++w) { wpref[w] = run; run += ws[w]; }
    blocksums[blockIdx.x] = run;
  }
  __syncthreads();
  if (i < NN) loc[i] = x - v + wpref[wid];
}

// also finalizes the self-loop scalars
__global__ __launch_bounds__(256) void k_scanB(int* __restrict__ blocksums, int* __restrict__ offa,
                                               float* __restrict__ small) {
  int tid = threadIdx.x;
  int v = (tid < SCAN_NB) ? blocksums[tid] : 0;
  int lane = tid & 63, wid = tid >> 6;
  int x = v;
  #pragma unroll
  for (int d = 1; d < 64; d <<= 1) {
    int y = __shfl_up(x, d);
    if (lane >= d) x += y;
  }
  __shared__ int ws[4], wpref[4];
  if (lane == 63) ws[wid] = x;
  __syncthreads();
  if (tid == 0) {
    int run = 0;
    #pragma unroll
    for (int w = 0; w < 4; ++w) { wpref[w] = run; run += ws[w]; }
    offa[NN] = run;   // == NE
    small[194] = small[228] * (1.0f / NE);
    small[195] = small[229] * (1.0f / NE);
  }
  __syncthreads();
  if (tid < SCAN_NB) blocksums[tid] = x - v + wpref[wid];
}

__global__ __launch_bounds__(256) void k_scanC(int* __restrict__ offa, const int* __restrict__ blocksums) {
  int i = blockIdx.x * 256 + threadIdx.x;
  if (i < NN) offa[i] = offa[i] + blocksums[blockIdx.x];
}

// FUSED: blocks [0, EP_NB) run edgepre (LDS-staged attr dots, rank atomic, sums/maxes);
// blocks [EP_NB, EP_NB+GM_NB) run the independent layer-1 GEMM h1 = x @ W1^T (+ asd epilogue).
// The GEMM's FMA-dense blocks fill the latency gaps of edgepre's 30%-occupancy stream.
__global__ __launch_bounds__(256) void k_fused0(const float* __restrict__ attr,
                                                const int* __restrict__ col,
                                                const float* __restrict__ small,
                                                float* __restrict__ a_e1, float* __restrict__ a_e2,
                                                int* __restrict__ rank,
                                                int* __restrict__ counts,
                                                float* __restrict__ sums,
                                                unsigned* __restrict__ maxi,
                                                const float* __restrict__ x, const float* __restrict__ W1,
                                                float* __restrict__ h1,
                                                const float* __restrict__ as, const float* __restrict__ ad,
                                                float* __restrict__ asrc, float* __restrict__ adst) {
  __shared__ float smem[8704];   // edgepre: 8448 sattr + 16 redbuf | gemm: 2x 64x68 tiles
  int tid = threadIdx.x;
  if (blockIdx.x < EP_NB) {
    float* sattr = smem;
    float* redbuf = smem + 8448;
    float sp1[32], sp2[32];
    #pragma unroll
    for (int j = 0; j < 8; ++j) {
      float4 v1 = ((const float4*)(small + 128))[j];
      float4 v2 = ((const float4*)(small + 160))[j];
      sp1[j*4+0] = v1.x; sp1[j*4+1] = v1.y; sp1[j*4+2] = v1.z; sp1[j*4+3] = v1.w;
      sp2[j*4+0] = v2.x; sp2[j*4+1] = v2.y; sp2[j*4+2] = v2.z; sp2[j*4+3] = v2.w;
    }
    float c1 = small[192], c2 = small[193];
    int e = blockIdx.x * 256 + tid;
    int c = col[e];   // issue early
    const float4* ain = (const float4*)(attr + (size_t)blockIdx.x * 256 * FE);
    #pragma unroll
    for (int it = 0; it < 8; ++it) {
      int idx = it * 256 + tid;
      float4 v = ain[idx];
      int r = idx >> 3, ch = idx & 7;
      float* dst = &sattr[r * 33 + ch * 4];
      dst[0] = v.x; dst[1] = v.y; dst[2] = v.z; dst[3] = v.w;
    }
    __syncthreads();
    const float* myrow = &sattr[tid * 33];
    float d1 = c1, d2 = c2;
    #pragma unroll
    for (int j = 0; j < 32; ++j) {
      float a = myrow[j];
      d1 += a * sp1[j];
      d2 += a * sp2[j];
    }
    a_e1[e] = d1;
    a_e2[e] = d2;
    rank[e] = atomicAdd(&counts[c], 1);
    float s1 = d1, s2 = d2, m1 = d1, m2 = d2;
    #pragma unroll
    for (int m = 32; m; m >>= 1) {
      s1 += __shfl_xor(s1, m); s2 += __shfl_xor(s2, m);
      m1 = fmaxf(m1, __shfl_xor(m1, m)); m2 = fmaxf(m2, __shfl_xor(m2, m));
    }
    int wid = tid >> 6;
    if ((tid & 63) == 0) { redbuf[wid] = s1; redbuf[4 + wid] = s2; redbuf[8 + wid] = m1; redbuf[12 + wid] = m2; }
    __syncthreads();
    if (tid == 0) atomicAdd(&sums[0], redbuf[0] + redbuf[1] + redbuf[2] + redbuf[3]);
    if (tid == 1) atomicAdd(&sums[1], redbuf[4] + redbuf[5] + redbuf[6] + redbuf[7]);
    if (tid == 2) atomicMax(&maxi[2], omap(fmaxf(fmaxf(redbuf[8], redbuf[9]), fmaxf(redbuf[10], redbuf[11]))));
    if (tid == 3) atomicMax(&maxi[3], omap(fmaxf(fmaxf(redbuf[12], redbuf[13]), fmaxf(redbuf[14], redbuf[15]))));
  } else {
    // layer-1 GEMM: h1[NN][64] = x[NN][128] @ W1[64][128]^T, asd epilogue -> asrc/adst/maxi[0]
    float (*At)[68] = (float(*)[68])smem;
    float (*Bt)[68] = (float(*)[68])(smem + 4352);
    int m0 = (blockIdx.x - EP_NB) * 64;
    float acc[4][4] = {};
    for (int kc = 0; kc < 128; kc += 64) {
      #pragma unroll
      for (int it = 0; it < 4; ++it) {
        int idx = it * 256 + tid;
        int m = idx & 63, kv = idx >> 6;
        float4 bv = ((const float4*)(W1 + (size_t)m * 128 + kc))[kv];
        Bt[kv*4+0][m] = bv.x; Bt[kv*4+1][m] = bv.y; Bt[kv*4+2][m] = bv.z; Bt[kv*4+3][m] = bv.w;
        int gm = m0 + m;
        float4 av = make_float4(0.f, 0.f, 0.f, 0.f);
        if (gm < NN) av = ((const float4*)(x + (size_t)gm * 128 + kc))[kv];
        At[kv*4+0][m] = av.x; At[kv*4+1][m] = av.y; At[kv*4+2][m] = av.z; At[kv*4+3][m] = av.w;
      }
      __syncthreads();
      int tn = tid & 15, tm = tid >> 4;
      #pragma unroll 8
      for (int k = 0; k < 64; ++k) {
        float4 a4 = *(const float4*)&At[k][tm * 4];
        float4 b4 = *(const float4*)&Bt[k][tn * 4];
        acc[0][0] += a4.x*b4.x; acc[0][1] += a4.x*b4.y; acc[0][2] += a4.x*b4.z; acc[0][3] += a4.x*b4.w;
        acc[1][0] += a4.y*b4.x; acc[1][1] += a4.y*b4.y; acc[1][2] += a4.y*b4.z; acc[1][3] += a4.y*b4.w;
        acc[2][0] += a4.z*b4.x; acc[2][1] += a4.z*b4.y; acc[2][2] += a4.z*b4.z; acc[2][3] += a4.z*b4.w;
        acc[3][0] += a4.w*b4.x; acc[3][1] += a4.w*b4.y; acc[3][2] += a4.w*b4.z; acc[3][3] += a4.w*b4.w;
      }
      __syncthreads();
    }
    int tn = tid & 15, tm = tid >> 4;
    #pragma unroll
    for (int i = 0; i < 4; ++i) {
      int gm = m0 + tm * 4 + i;
      if (gm < NN) {
        float4 o = make_float4(acc[i][0], acc[i][1], acc[i][2], acc[i][3]);
        *(float4*)(h1 + (size_t)gm * 64 + tn * 4) = o;
      }
    }
    __shared__ float wmax[4];
    float4 asv = ((const float4*)as)[tn];
    float4 adv = ((const float4*)ad)[tn];
    float smax = -1e30f;
    #pragma unroll
    for (int i = 0; i < 4; ++i) {
      float s = acc[i][0]*asv.x + acc[i][1]*asv.y + acc[i][2]*asv.z + acc[i][3]*asv.w;
      float d = acc[i][0]*adv.x + acc[i][1]*adv.y + acc[i][2]*adv.z + acc[i][3]*adv.w;
      #pragma unroll
      for (int m = 8; m; m >>= 1) { s += __shfl_xor(s, m, 16); d += __shfl_xor(d, m, 16); }
      int gm = m0 + tm * 4 + i;
      if (tn == 0 && gm < NN) { asrc[gm] = s; adst[gm] = d; smax = fmaxf(smax, s); }
    }
    #pragma unroll
    for (int m = 32; m; m >>= 1) smax = fmaxf(smax, __shfl_xor(smax, m));
    if ((tid & 63) == 0) wmax[tid >> 6] = smax;
    __syncthreads();
    if (tid == 0)
      atomicMax(&maxi[0], omap(fmaxf(fmaxf(wmax[0], wmax[1]), fmaxf(wmax[2], wmax[3]))));
  }
}

// atomic-free scatter, 2 independent edge-chains per thread (MLP), guarded tail
__global__ __launch_bounds__(256) void k_scatter(const int* __restrict__ row, const int* __restrict__ col,
                                                 const float* __restrict__ a_e1, const float* __restrict__ a_e2,
                                                 const int* __restrict__ rank, const int* __restrict__ offa,
                                                 int4* __restrict__ pk) {
  int t = blockIdx.x * 256 + threadIdx.x;
  if (t >= NE / 2) return;
  int e0 = t, e1 = t + NE / 2;
  int c0 = col[e0], c1 = col[e1];
  int r0 = rank[e0], r1 = rank[e1];
  int o0 = offa[c0], o1 = offa[c1];
  int4 q0, q1;
  q0.x = row[e0]; q0.y = __float_as_int(a_e1[e0]); q0.z = __float_as_int(a_e2[e0]); q0.w = 0;
  q1.x = row[e1]; q1.y = __float_as_int(a_e1[e1]); q1.z = __float_as_int(a_e2[e1]); q1.w = 0;
  pk[o0 + r0] = q0;
  pk[o1 + r1] = q1;
}

// C[M][ldc-tile] = A[M][K] * B^T, B is [64][K] row-major (per blockIdx.y tile)
// ASD: also emit asrc/adst from the accumulator tile + global max(asrc) -> maxslot
template <int K, int ASD>
__global__ __launch_bounds__(256) void k_gemm(const float* __restrict__ A, const float* __restrict__ B,
                                              float* __restrict__ C, int M, int ldc,
                                              const float* __restrict__ as, const float* __restrict__ ad,
                                              float* __restrict__ asrc, float* __restrict__ adst,
                                              unsigned* __restrict__ maxslot) {
  __shared__ float At[64][68];
  __shared__ float Bt[64][68];
  int tid = threadIdx.x;
  int m0 = blockIdx.x * 64;
  const float* Bp = B + (size_t)blockIdx.y * 64 * K;
  float acc[4][4] = {};
  for (int kc = 0; kc < K; kc += 64) {
    #pragma unroll
    for (int it = 0; it < 4; ++it) {
      int idx = it * 256 + tid;
      int m = idx & 63, kv = idx >> 6;  // kv in 0..15
      float4 bv = ((const float4*)(Bp + (size_t)m * K + kc))[kv];
      Bt[kv*4+0][m] = bv.x; Bt[kv*4+1][m] = bv.y; Bt[kv*4+2][m] = bv.z; Bt[kv*4+3][m] = bv.w;
      int gm = m0 + m;
      float4 av = make_float4(0.f, 0.f, 0.f, 0.f);
      if (gm < M) av = ((const float4*)(A + (size_t)gm * K + kc))[kv];
      At[kv*4+0][m] = av.x; At[kv*4+1][m] = av.y; At[kv*4+2][m] = av.z; At[kv*4+3][m] = av.w;
    }
    __syncthreads();
    int tn = tid & 15, tm = tid >> 4;
    #pragma unroll 8
    for (int k = 0; k < 64; ++k) {
      float4 a4 = *(const float4*)&At[k][tm * 4];
      float4 b4 = *(const float4*)&Bt[k][tn * 4];
      acc[0][0] += a4.x*b4.x; acc[0][1] += a4.x*b4.y; acc[0][2] += a4.x*b4.z; acc[0][3] += a4.x*b4.w;
      acc[1][0] += a4.y*b4.x; acc[1][1] += a4.y*b4.y; acc[1][2] += a4.y*b4.z; acc[1][3] += a4.y*b4.w;
      acc[2][0] += a4.z*b4.x; acc[2][1] += a4.z*b4.y; acc[2][2] += a4.z*b4.z; acc[2][3] += a4.z*b4.w;
      acc[3][0] += a4.w*b4.x; acc[3][1] += a4.w*b4.y; acc[3][2] += a4.w*b4.z; acc[3][3] += a4.w*b4.w;
    }
    __syncthreads();
  }
  int tn = tid & 15, tm = tid >> 4;
  #pragma unroll
  for (int i = 0; i < 4; ++i) {
    int gm = m0 + tm * 4 + i;
    if (gm < M) {
      float4 o = make_float4(acc[i][0], acc[i][1], acc[i][2], acc[i][3]);
      *(float4*)(C + (size_t)gm * ldc + blockIdx.y * 64 + tn * 4) = o;
    }
  }
  if constexpr (ASD) {
    __shared__ float wmax[4];
    float4 asv = ((const float4*)as)[tn];
    float4 adv = ((const float4*)ad)[tn];
    float smax = -1e30f;
    #pragma unroll
    for (int i = 0; i < 4; ++i) {
      float s = acc[i][0]*asv.x + acc[i][1]*asv.y + acc[i][2]*asv.z + acc[i][3]*asv.w;
      float d = acc[i][0]*adv.x + acc[i][1]*adv.y + acc[i][2]*adv.z + acc[i][3]*adv.w;
      #pragma unroll
      for (int m = 8; m; m >>= 1) { s += __shfl_xor(s, m, 16); d += __shfl_xor(d, m, 16); }
      int gm = m0 + tm * 4 + i;
      if (tn == 0 && gm < M) { asrc[gm] = s; adst[gm] = d; smax = fmaxf(smax, s); }
    }
    #pragma unroll
    for (int m = 32; m; m >>= 1) smax = fmaxf(smax, __shfl_xor(smax, m));
    if ((tid & 63) == 0) wmax[tid >> 6] = smax;
    __syncthreads();
    if (tid == 0)
      atomicMax(maxslot, omap(fmaxf(fmaxf(wmax[0], wmax[1]), fmaxf(wmax[2], wmax[3]))));
  }
}

// one wave per destination node, SINGLE PASS softmax (global-bound shift),
// 4-way unrolled gather loop with independent accumulators (ILP for load latency).
__global__ __launch_bounds__(256) void k_agg(const float* __restrict__ h, const int* __restrict__ offa,
                                             const int4* __restrict__ pk, int comp,
                                             const float* __restrict__ asrc, const float* __restrict__ adst,
                                             const float* __restrict__ small, int selfIdx,
                                             const unsigned* __restrict__ maxi,
                                             const float* __restrict__ bias, float* __restrict__ outp,
                                             int do_relu) {
  int gt = blockIdx.x * 256 + threadIdx.x;
  int n = gt >> 6, lane = gt & 63;
  if (n >= NN) return;
  int beg = offa[n], end = offa[n + 1];
  float adn = adst[n];
  // shift bound: m >= every alpha in this segment (softmax is shift-invariant)
  float mx = lrelu(odec(maxi[comp]) + adn + odec(maxi[2 + comp]));
  float alpha_self = lrelu(asrc[n] + adn + small[selfIdx]);
  float ex_self = __expf(alpha_self - mx);
  float denom = ex_self;
  float acc0 = ex_self * h[(size_t)n * 64 + lane];
  float acc1 = 0.f, acc2 = 0.f, acc3 = 0.f;
  for (int base = beg; base < end; base += 64) {
    int p = base + lane;
    int cnt = min(64, end - base);
    float ex = 0.f; int s = 0;
    if (p < end) {
      int4 q = pk[p];
      s = q.x;
      float ae = __int_as_float(comp ? q.z : q.y);
      ex = __expf(lrelu(asrc[s] + adn + ae) - mx);
    }
    float exs = ex;
    #pragma unroll
    for (int m = 32; m; m >>= 1) exs += __shfl_xor(exs, m);
    denom += exs;
    int q4 = cnt & ~3;
    for (int q = 0; q < q4; q += 4) {
      float e0 = __shfl(ex, q),     e1 = __shfl(ex, q + 1);
      float e2 = __shfl(ex, q + 2), e3 = __shfl(ex, q + 3);
      int s0 = __shfl(s, q),     s1 = __shfl(s, q + 1);
      int s2 = __shfl(s, q + 2), s3 = __shfl(s, q + 3);
      acc0 += e0 * h[(size_t)s0 * 64 + lane];
      acc1 += e1 * h[(size_t)s1 * 64 + lane];
      acc2 += e2 * h[(size_t)s2 * 64 + lane];
      acc3 += e3 * h[(size_t)s3 * 64 + lane];
    }
    for (int q = q4; q < cnt; ++q) {
      float eq = __shfl(ex, q);
      int sq = __shfl(s, q);
      acc0 += eq * h[(size_t)sq * 64 + lane];
    }
  }
  float r = (acc0 + acc1 + acc2 + acc3) / denom + bias[lane];
  if (do_relu) r = fmaxf(r, 0.f);
  outp[(size_t)n * 64 + lane] = r;
}

// edge scorer: 16 lanes per edge
__global__ __launch_bounds__(256) void k_final(const int* __restrict__ row, const int* __restrict__ col,
                                               const float* __restrict__ uv, const float* __restrict__ s1b,
                                               const float* __restrict__ s2w, const float* __restrict__ s2b,
                                               float* __restrict__ outp) {
  int gt = blockIdx.x * 256 + threadIdx.x;
  int e = gt >> 4, i = gt & 15;
  if (e >= NE) return;
  int r = row[e], c = col[e];
  float4 a = ((const float4*)(uv + (size_t)r * 128))[i];
  float4 b = ((const float4*)(uv + (size_t)c * 128 + 64))[i];
  float4 bb = ((const float4*)s1b)[i];
  float4 ww = ((const float4*)s2w)[i];
  float z = fmaxf(a.x + b.x + bb.x, 0.f) * ww.x
          + fmaxf(a.y + b.y + bb.y, 0.f) * ww.y
          + fmaxf(a.z + b.z + bb.z, 0.f) * ww.z
          + fmaxf(a.w + b.w + bb.w, 0.f) * ww.w;
  #pragma unroll
  for (int m = 1; m < 16; m <<= 1) z += __shfl_xor(z, m, 16);
  if (i == 0) outp[e] = 1.f / (1.f + __expf(-(z + s2b[0])));
}

extern "C" void kernel_launch(void* const* d_in, const int* in_sizes, int n_in,
                              void* d_out, int out_size, void* d_ws, size_t ws_size,
                              hipStream_t stream) {
  const float* x    = (const float*)d_in[0];
  const float* attr = (const float*)d_in[1];
  const int*   eidx = (const int*)d_in[2];   // [2][NE]: row then col
  const float* encW = (const float*)d_in[3];
  const float* encb = (const float*)d_in[4];
  const float* W1   = (const float*)d_in[5];
  const float* le1W = (const float*)d_in[6];
  const float* as1  = (const float*)d_in[7];
  const float* ad1  = (const float*)d_in[8];
  const float* ae1w = (const float*)d_in[9];
  const float* b1   = (const float*)d_in[10];
  const float* W2   = (const float*)d_in[11];
  const float* le2W = (const float*)d_in[12];
  const float* as2  = (const float*)d_in[13];
  const float* ad2  = (const float*)d_in[14];
  const float* ae2w = (const float*)d_in[15];
  const float* b2   = (const float*)d_in[16];
  const float* s1W  = (const float*)d_in[17];
  const float* s1b  = (const float*)d_in[18];
  const float* s2w  = (const float*)d_in[19];
  const float* s2b  = (const float*)d_in[20];
  float* outp = (float*)d_out;

  const int* row = eidx;
  const int* col = eidx + NE;

  char* p = (char*)d_ws;
  auto alloc = [&](size_t bytes) { char* r = p; p += (bytes + 255) & ~(size_t)255; return r; };
  float* small = (float*)alloc(1024);
  unsigned* maxi = (unsigned*)alloc(256);
  float* Scomb = (float*)alloc(8192 * 4);
  int*   counts= (int*)alloc((size_t)NN * 4);
  int*   offa  = (int*)alloc((size_t)(NN + 1) * 4);
  int*   bsums = (int*)alloc((size_t)SCAN_NB * 4);
  float* a_e1  = (float*)alloc((size_t)NE * 4);
  float* a_e2  = (float*)alloc((size_t)NE * 4);
  int*   rank  = (int*)alloc((size_t)NE * 4);
  int4*  pk    = (int4*)alloc((size_t)NE * 16);
  float* h1    = (float*)alloc((size_t)NN * 64 * 4);
  float* out1  = (float*)alloc((size_t)NN * 64 * 4);   // contiguous after h1
  float* h2    = (float*)alloc((size_t)NN * 64 * 4);
  float* out2  = (float*)alloc((size_t)NN * 64 * 4);
  float* asrc1 = (float*)alloc((size_t)NN * 4);
  float* adst1 = (float*)alloc((size_t)NN * 4);
  float* asrc2 = (float*)alloc((size_t)NN * 4);
  float* adst2 = (float*)alloc((size_t)NN * 4);
  float* uv = h1;  // [NN][128], reuses h1||out1 (both dead by then)

  hipMemsetAsync(small, 0, 1024, stream);
  hipMemsetAsync(maxi, 0, 256, stream);
  hipMemsetAsync(counts, 0, (size_t)NN * 4, stream);

  k_small0<<<1, 64, 0, stream>>>(le1W, ae1w, le2W, ae2w, encW, encb, s1W, small, Scomb);
  // fused: edgepre (3125 blocks) + layer-1 GEMM (782 blocks)
  k_fused0<<<EP_NB + GM_NB, 256, 0, stream>>>(attr, col, small, a_e1, a_e2, rank, counts,
                                              small + 228, maxi, x, W1, h1, as1, ad1, asrc1, adst1);
  k_scanA<<<SCAN_NB, 256, 0, stream>>>(counts, offa, bsums);
  k_scanB<<<1, 256, 0, stream>>>(bsums, offa, small);
  k_scanC<<<SCAN_NB, 256, 0, stream>>>(offa, bsums);
  k_scatter<<<(NE / 2 + 255) / 256, 256, 0, stream>>>(row, col, a_e1, a_e2, rank, offa, pk);

  // layer 1 aggregation
  k_agg<<<(NN * 64) / 256, 256, 0, stream>>>(h1, offa, pk, 0, asrc1, adst1,
                                             small, 194, maxi, b1, out1, 1);
  // layer 2
  k_gemm<64, 1><<<dim3((NN + 63) / 64, 1), 256, 0, stream>>>(out1, W2, h2, NN, 64, as2, ad2, asrc2, adst2, maxi + 1);
  k_agg<<<(NN * 64) / 256, 256, 0, stream>>>(h2, offa, pk, 1, asrc2, adst2,
                                             small, 195, maxi, b2, out2, 0);
  // scorer: uv = [u | v]
  k_gemm<64, 0><<<dim3((NN + 63) / 64, 2), 256, 0, stream>>>(out2, Scomb, uv, NN, 128, nullptr, nullptr, nullptr, nullptr, nullptr);
  k_final<<<(NE * 16) / 256, 256, 0, stream>>>(row, col, uv, s1b, s2w, s2b, outp);
}

// Round 13
// 303.959 us; speedup vs baseline: 1.3353x; 1.0483x over previous
//
#include <hip/hip_runtime.h>
#include <cstdint>
#include <cstddef>

#define NN 50000
#define NE 800000
#define FN 128
#define FE 32
#define HD 64
#define SCAN_NB ((NN + 255) / 256)   // 196
#define EP_NB (NE / 256)             // 3125 edgepre blocks
#define GM_NB ((NN + 63) / 64)       // 782 gemm blocks

__device__ __forceinline__ float lrelu(float x) { return x > 0.f ? x : 0.2f * x; }

// order-preserving float<->uint map for atomicMax on floats (0 == -inf sentinel)
__device__ __forceinline__ unsigned omap(float f) {
  unsigned u = __float_as_uint(f);
  return (u & 0x80000000u) ? ~u : (u | 0x80000000u);
}
__device__ __forceinline__ float odec(unsigned u) {
  return __uint_as_float((u & 0x80000000u) ? (u ^ 0x80000000u) : ~u);
}

// small[] layout (floats): 0..63 vec1 | 64..127 vec2 | 128..159 p1 | 160..191 p2
// 192 c1 | 193 c2 | 194 a_self1 | 195 a_self2 | 228 sum_d1 | 229 sum_d2
// maxi[] (uint): 0 Mas1 | 1 Mas2 | 2 Mae1 | 3 Mae2
__global__ void k_small0(const float* __restrict__ le1W, const float* __restrict__ ae1,
                         const float* __restrict__ le2W, const float* __restrict__ ae2,
                         const float* __restrict__ encW, const float* __restrict__ encb,
                         const float* __restrict__ s1W,
                         float* __restrict__ small, float* __restrict__ Scomb) {
  __shared__ float sv1[64], sv2[64];
  int t = threadIdx.x;  // 64 threads = 1 wave
  float v1 = 0.f, v2 = 0.f;
  for (int j = 0; j < 64; ++j) {
    v1 += le1W[j * 64 + t] * ae1[j];
    v2 += le2W[j * 64 + t] * ae2[j];
  }
  sv1[t] = v1; sv2[t] = v2;
  small[t] = v1; small[64 + t] = v2;
  float cb1 = encb[t] * v1, cb2 = encb[t] * v2;
  #pragma unroll
  for (int m = 32; m; m >>= 1) { cb1 += __shfl_xor(cb1, m); cb2 += __shfl_xor(cb2, m); }
  __syncthreads();
  if (t < 32) {
    float p1 = 0.f, p2 = 0.f;
    for (int i = 0; i < 64; ++i) {
      p1 += encW[i * 32 + t] * sv1[i];
      p2 += encW[i * 32 + t] * sv2[i];
    }
    small[128 + t] = p1; small[160 + t] = p2;
  }
  if (t == 0) { small[192] = cb1; small[193] = cb2; }
  // Scomb[128][64]: rows 0..63 = s1_W[:, :64]; rows 64..127 = s1_W[:, 64:]
  for (int j = 0; j < 64; ++j) {
    Scomb[j * 64 + t] = s1W[j * 128 + t];
    Scomb[(64 + j) * 64 + t] = s1W[j * 128 + 64 + t];
  }
}

// hierarchical exclusive scan of counts -> offa, offa[NN]=NE
__global__ __launch_bounds__(256) void k_scanA(const int* __restrict__ counts,
                                               int* __restrict__ loc, int* __restrict__ blocksums) {
  int tid = threadIdx.x;
  int i = blockIdx.x * 256 + tid;
  int v = (i < NN) ? counts[i] : 0;
  int lane = tid & 63, wid = tid >> 6;
  int x = v;
  #pragma unroll
  for (int d = 1; d < 64; d <<= 1) {
    int y = __shfl_up(x, d);
    if (lane >= d) x += y;
  }
  __shared__ int ws[4], wpref[4];
  if (lane == 63) ws[wid] = x;
  __syncthreads();
  if (tid == 0) {
    int run = 0;
    #pragma unroll
    for (int w = 0; w < 4; ++w) { wpref[w] = run; run += ws[w]; }
    blocksums[blockIdx.x] = run;
  }
  __syncthreads();
  if (i < NN) loc[i] = x - v + wpref[wid];
}

// also finalizes the self-loop scalars
__global__ __launch_bounds__(256) void k_scanB(int* __restrict__ blocksums, int* __restrict__ offa,
                                               float* __restrict__ small) {
  int tid = threadIdx.x;
  int v = (tid < SCAN_NB) ? blocksums[tid] : 0;
  int lane = tid & 63, wid = tid >> 6;
  int x = v;
  #pragma unroll
  for (int d = 1; d < 64; d <<= 1) {
    int y = __shfl_up(x, d);
    if (lane >= d) x += y;
  }
  __shared__ int ws[4], wpref[4];
  if (lane == 63) ws[wid] = x;
  __syncthreads();
  if (tid == 0) {
    int run = 0;
    #pragma unroll
    for (int w = 0; w < 4; ++w) { wpref[w] = run; run += ws[w]; }
    offa[NN] = run;   // == NE
    small[194] = small[228] * (1.0f / NE);
    small[195] = small[229] * (1.0f / NE);
  }
  __syncthreads();
  if (tid < SCAN_NB) blocksums[tid] = x - v + wpref[wid];
}

__global__ __launch_bounds__(256) void k_scanC(int* __restrict__ offa, const int* __restrict__ blocksums) {
  int i = blockIdx.x * 256 + threadIdx.x;
  if (i < NN) offa[i] = offa[i] + blocksums[blockIdx.x];
}

// FUSED: blocks [0, EP_NB) run edgepre (LDS-staged attr dots, rank atomic, sums/maxes);
// blocks [EP_NB, EP_NB+GM_NB) run the independent layer-1 GEMM h1 = x @ W1^T (+ asd epilogue).
__global__ __launch_bounds__(256) void k_fused0(const float* __restrict__ attr,
                                                const int* __restrict__ col,
                                                const float* __restrict__ small,
                                                float* __restrict__ a_e1, float* __restrict__ a_e2,
                                                int* __restrict__ rank,
                                                int* __restrict__ counts,
                                                float* __restrict__ sums,
                                                unsigned* __restrict__ maxi,
                                                const float* __restrict__ x, const float* __restrict__ W1,
                                                float* __restrict__ h1,
                                                const float* __restrict__ as, const float* __restrict__ ad,
                                                float* __restrict__ asrc, float* __restrict__ adst) {
  __shared__ float smem[8704];   // edgepre: 8448 sattr + 16 redbuf | gemm: 2x 64x68 tiles
  int tid = threadIdx.x;
  if (blockIdx.x < EP_NB) {
    float* sattr = smem;
    float* redbuf = smem + 8448;
    float sp1[32], sp2[32];
    #pragma unroll
    for (int j = 0; j < 8; ++j) {
      float4 v1 = ((const float4*)(small + 128))[j];
      float4 v2 = ((const float4*)(small + 160))[j];
      sp1[j*4+0] = v1.x; sp1[j*4+1] = v1.y; sp1[j*4+2] = v1.z; sp1[j*4+3] = v1.w;
      sp2[j*4+0] = v2.x; sp2[j*4+1] = v2.y; sp2[j*4+2] = v2.z; sp2[j*4+3] = v2.w;
    }
    float c1 = small[192], c2 = small[193];
    int e = blockIdx.x * 256 + tid;
    int c = col[e];   // issue early
    const float4* ain = (const float4*)(attr + (size_t)blockIdx.x * 256 * FE);
    #pragma unroll
    for (int it = 0; it < 8; ++it) {
      int idx = it * 256 + tid;
      float4 v = ain[idx];
      int r = idx >> 3, ch = idx & 7;
      float* dst = &sattr[r * 33 + ch * 4];
      dst[0] = v.x; dst[1] = v.y; dst[2] = v.z; dst[3] = v.w;
    }
    __syncthreads();
    const float* myrow = &sattr[tid * 33];
    float d1 = c1, d2 = c2;
    #pragma unroll
    for (int j = 0; j < 32; ++j) {
      float a = myrow[j];
      d1 += a * sp1[j];
      d2 += a * sp2[j];
    }
    a_e1[e] = d1;
    a_e2[e] = d2;
    rank[e] = atomicAdd(&counts[c], 1);
    float s1 = d1, s2 = d2, m1 = d1, m2 = d2;
    #pragma unroll
    for (int m = 32; m; m >>= 1) {
      s1 += __shfl_xor(s1, m); s2 += __shfl_xor(s2, m);
      m1 = fmaxf(m1, __shfl_xor(m1, m)); m2 = fmaxf(m2, __shfl_xor(m2, m));
    }
    int wid = tid >> 6;
    if ((tid & 63) == 0) { redbuf[wid] = s1; redbuf[4 + wid] = s2; redbuf[8 + wid] = m1; redbuf[12 + wid] = m2; }
    __syncthreads();
    if (tid == 0) atomicAdd(&sums[0], redbuf[0] + redbuf[1] + redbuf[2] + redbuf[3]);
    if (tid == 1) atomicAdd(&sums[1], redbuf[4] + redbuf[5] + redbuf[6] + redbuf[7]);
    if (tid == 2) atomicMax(&maxi[2], omap(fmaxf(fmaxf(redbuf[8], redbuf[9]), fmaxf(redbuf[10], redbuf[11]))));
    if (tid == 3) atomicMax(&maxi[3], omap(fmaxf(fmaxf(redbuf[12], redbuf[13]), fmaxf(redbuf[14], redbuf[15]))));
  } else {
    // layer-1 GEMM: h1[NN][64] = x[NN][128] @ W1[64][128]^T, asd epilogue -> asrc/adst/maxi[0]
    float (*At)[68] = (float(*)[68])smem;
    float (*Bt)[68] = (float(*)[68])(smem + 4352);
    int m0 = (blockIdx.x - EP_NB) * 64;
    float acc[4][4] = {};
    for (int kc = 0; kc < 128; kc += 64) {
      #pragma unroll
      for (int it = 0; it < 4; ++it) {
        int idx = it * 256 + tid;
        int m = idx & 63, kv = idx >> 6;
        float4 bv = ((const float4*)(W1 + (size_t)m * 128 + kc))[kv];
        Bt[kv*4+0][m] = bv.x; Bt[kv*4+1][m] = bv.y; Bt[kv*4+2][m] = bv.z; Bt[kv*4+3][m] = bv.w;
        int gm = m0 + m;
        float4 av = make_float4(0.f, 0.f, 0.f, 0.f);
        if (gm < NN) av = ((const float4*)(x + (size_t)gm * 128 + kc))[kv];
        At[kv*4+0][m] = av.x; At[kv*4+1][m] = av.y; At[kv*4+2][m] = av.z; At[kv*4+3][m] = av.w;
      }
      __syncthreads();
      int tn = tid & 15, tm = tid >> 4;
      #pragma unroll 8
      for (int k = 0; k < 64; ++k) {
        float4 a4 = *(const float4*)&At[k][tm * 4];
        float4 b4 = *(const float4*)&Bt[k][tn * 4];
        acc[0][0] += a4.x*b4.x; acc[0][1] += a4.x*b4.y; acc[0][2] += a4.x*b4.z; acc[0][3] += a4.x*b4.w;
        acc[1][0] += a4.y*b4.x; acc[1][1] += a4.y*b4.y; acc[1][2] += a4.y*b4.z; acc[1][3] += a4.y*b4.w;
        acc[2][0] += a4.z*b4.x; acc[2][1] += a4.z*b4.y; acc[2][2] += a4.z*b4.z; acc[2][3] += a4.z*b4.w;
        acc[3][0] += a4.w*b4.x; acc[3][1] += a4.w*b4.y; acc[3][2] += a4.w*b4.z; acc[3][3] += a4.w*b4.w;
      }
      __syncthreads();
    }
    int tn = tid & 15, tm = tid >> 4;
    #pragma unroll
    for (int i = 0; i < 4; ++i) {
      int gm = m0 + tm * 4 + i;
      if (gm < NN) {
        float4 o = make_float4(acc[i][0], acc[i][1], acc[i][2], acc[i][3]);
        *(float4*)(h1 + (size_t)gm * 64 + tn * 4) = o;
      }
    }
    __shared__ float wmax[4];
    float4 asv = ((const float4*)as)[tn];
    float4 adv = ((const float4*)ad)[tn];
    float smax = -1e30f;
    #pragma unroll
    for (int i = 0; i < 4; ++i) {
      float s = acc[i][0]*asv.x + acc[i][1]*asv.y + acc[i][2]*asv.z + acc[i][3]*asv.w;
      float d = acc[i][0]*adv.x + acc[i][1]*adv.y + acc[i][2]*adv.z + acc[i][3]*adv.w;
      #pragma unroll
      for (int m = 8; m; m >>= 1) { s += __shfl_xor(s, m, 16); d += __shfl_xor(d, m, 16); }
      int gm = m0 + tm * 4 + i;
      if (tn == 0 && gm < NN) { asrc[gm] = s; adst[gm] = d; smax = fmaxf(smax, s); }
    }
    #pragma unroll
    for (int m = 32; m; m >>= 1) smax = fmaxf(smax, __shfl_xor(smax, m));
    if ((tid & 63) == 0) wmax[tid >> 6] = smax;
    __syncthreads();
    if (tid == 0)
      atomicMax(&maxi[0], omap(fmaxf(fmaxf(wmax[0], wmax[1]), fmaxf(wmax[2], wmax[3]))));
  }
}

// atomic-free scatter, 2 independent edge-chains per thread (MLP), guarded tail.
// pk[p] = {src, ae1_bits, ae2_bits, eid} — eid enables CSR-order k_final.
__global__ __launch_bounds__(256) void k_scatter(const int* __restrict__ row, const int* __restrict__ col,
                                                 const float* __restrict__ a_e1, const float* __restrict__ a_e2,
                                                 const int* __restrict__ rank, const int* __restrict__ offa,
                                                 int4* __restrict__ pk) {
  int t = blockIdx.x * 256 + threadIdx.x;
  if (t >= NE / 2) return;
  int e0 = t, e1 = t + NE / 2;
  int c0 = col[e0], c1 = col[e1];
  int r0 = rank[e0], r1 = rank[e1];
  int o0 = offa[c0], o1 = offa[c1];
  int4 q0, q1;
  q0.x = row[e0]; q0.y = __float_as_int(a_e1[e0]); q0.z = __float_as_int(a_e2[e0]); q0.w = e0;
  q1.x = row[e1]; q1.y = __float_as_int(a_e1[e1]); q1.z = __float_as_int(a_e2[e1]); q1.w = e1;
  pk[o0 + r0] = q0;
  pk[o1 + r1] = q1;
}

// C[M][ldc-tile] = A[M][K] * B^T, B is [64][K] row-major (per blockIdx.y tile)
// ASD: also emit asrc/adst from the accumulator tile + global max(asrc) -> maxslot
template <int K, int ASD>
__global__ __launch_bounds__(256) void k_gemm(const float* __restrict__ A, const float* __restrict__ B,
                                              float* __restrict__ C, int M, int ldc,
                                              const float* __restrict__ as, const float* __restrict__ ad,
                                              float* __restrict__ asrc, float* __restrict__ adst,
                                              unsigned* __restrict__ maxslot) {
  __shared__ float At[64][68];
  __shared__ float Bt[64][68];
  int tid = threadIdx.x;
  int m0 = blockIdx.x * 64;
  const float* Bp = B + (size_t)blockIdx.y * 64 * K;
  float acc[4][4] = {};
  for (int kc = 0; kc < K; kc += 64) {
    #pragma unroll
    for (int it = 0; it < 4; ++it) {
      int idx = it * 256 + tid;
      int m = idx & 63, kv = idx >> 6;  // kv in 0..15
      float4 bv = ((const float4*)(Bp + (size_t)m * K + kc))[kv];
      Bt[kv*4+0][m] = bv.x; Bt[kv*4+1][m] = bv.y; Bt[kv*4+2][m] = bv.z; Bt[kv*4+3][m] = bv.w;
      int gm = m0 + m;
      float4 av = make_float4(0.f, 0.f, 0.f, 0.f);
      if (gm < M) av = ((const float4*)(A + (size_t)gm * K + kc))[kv];
      At[kv*4+0][m] = av.x; At[kv*4+1][m] = av.y; At[kv*4+2][m] = av.z; At[kv*4+3][m] = av.w;
    }
    __syncthreads();
    int tn = tid & 15, tm = tid >> 4;
    #pragma unroll 8
    for (int k = 0; k < 64; ++k) {
      float4 a4 = *(const float4*)&At[k][tm * 4];
      float4 b4 = *(const float4*)&Bt[k][tn * 4];
      acc[0][0] += a4.x*b4.x; acc[0][1] += a4.x*b4.y; acc[0][2] += a4.x*b4.z; acc[0][3] += a4.x*b4.w;
      acc[1][0] += a4.y*b4.x; acc[1][1] += a4.y*b4.y; acc[1][2] += a4.y*b4.z; acc[1][3] += a4.y*b4.w;
      acc[2][0] += a4.z*b4.x; acc[2][1] += a4.z*b4.y; acc[2][2] += a4.z*b4.z; acc[2][3] += a4.z*b4.w;
      acc[3][0] += a4.w*b4.x; acc[3][1] += a4.w*b4.y; acc[3][2] += a4.w*b4.z; acc[3][3] += a4.w*b4.w;
    }
    __syncthreads();
  }
  int tn = tid & 15, tm = tid >> 4;
  #pragma unroll
  for (int i = 0; i < 4; ++i) {
    int gm = m0 + tm * 4 + i;
    if (gm < M) {
      float4 o = make_float4(acc[i][0], acc[i][1], acc[i][2], acc[i][3]);
      *(float4*)(C + (size_t)gm * ldc + blockIdx.y * 64 + tn * 4) = o;
    }
  }
  if constexpr (ASD) {
    __shared__ float wmax[4];
    float4 asv = ((const float4*)as)[tn];
    float4 adv = ((const float4*)ad)[tn];
    float smax = -1e30f;
    #pragma unroll
    for (int i = 0; i < 4; ++i) {
      float s = acc[i][0]*asv.x + acc[i][1]*asv.y + acc[i][2]*asv.z + acc[i][3]*asv.w;
      float d = acc[i][0]*adv.x + acc[i][1]*adv.y + acc[i][2]*adv.z + acc[i][3]*adv.w;
      #pragma unroll
      for (int m = 8; m; m >>= 1) { s += __shfl_xor(s, m, 16); d += __shfl_xor(d, m, 16); }
      int gm = m0 + tm * 4 + i;
      if (tn == 0 && gm < M) { asrc[gm] = s; adst[gm] = d; smax = fmaxf(smax, s); }
    }
    #pragma unroll
    for (int m = 32; m; m >>= 1) smax = fmaxf(smax, __shfl_xor(smax, m));
    if ((tid & 63) == 0) wmax[tid >> 6] = smax;
    __syncthreads();
    if (tid == 0)
      atomicMax(maxslot, omap(fmaxf(fmaxf(wmax[0], wmax[1]), fmaxf(wmax[2], wmax[3]))));
  }
}

// one wave per destination node, SINGLE PASS softmax (global-bound shift),
// 4-way unrolled gather loop with independent accumulators (ILP for load latency).
__global__ __launch_bounds__(256) void k_agg(const float* __restrict__ h, const int* __restrict__ offa,
                                             const int4* __restrict__ pk, int comp,
                                             const float* __restrict__ asrc, const float* __restrict__ adst,
                                             const float* __restrict__ small, int selfIdx,
                                             const unsigned* __restrict__ maxi,
                                             const float* __restrict__ bias, float* __restrict__ outp,
                                             int do_relu) {
  int gt = blockIdx.x * 256 + threadIdx.x;
  int n = gt >> 6, lane = gt & 63;
  if (n >= NN) return;
  int beg = offa[n], end = offa[n + 1];
  float adn = adst[n];
  // shift bound: m >= every alpha in this segment (softmax is shift-invariant)
  float mx = lrelu(odec(maxi[comp]) + adn + odec(maxi[2 + comp]));
  float alpha_self = lrelu(asrc[n] + adn + small[selfIdx]);
  float ex_self = __expf(alpha_self - mx);
  float denom = ex_self;
  float acc0 = ex_self * h[(size_t)n * 64 + lane];
  float acc1 = 0.f, acc2 = 0.f, acc3 = 0.f;
  for (int base = beg; base < end; base += 64) {
    int p = base + lane;
    int cnt = min(64, end - base);
    float ex = 0.f; int s = 0;
    if (p < end) {
      int4 q = pk[p];
      s = q.x;
      float ae = __int_as_float(comp ? q.z : q.y);
      ex = __expf(lrelu(asrc[s] + adn + ae) - mx);
    }
    float exs = ex;
    #pragma unroll
    for (int m = 32; m; m >>= 1) exs += __shfl_xor(exs, m);
    denom += exs;
    int q4 = cnt & ~3;
    for (int q = 0; q < q4; q += 4) {
      float e0 = __shfl(ex, q),     e1 = __shfl(ex, q + 1);
      float e2 = __shfl(ex, q + 2), e3 = __shfl(ex, q + 3);
      int s0 = __shfl(s, q),     s1 = __shfl(s, q + 1);
      int s2 = __shfl(s, q + 2), s3 = __shfl(s, q + 3);
      acc0 += e0 * h[(size_t)s0 * 64 + lane];
      acc1 += e1 * h[(size_t)s1 * 64 + lane];
      acc2 += e2 * h[(size_t)s2 * 64 + lane];
      acc3 += e3 * h[(size_t)s3 * 64 + lane];
    }
    for (int q = q4; q < cnt; ++q) {
      float eq = __shfl(ex, q);
      int sq = __shfl(s, q);
      acc0 += eq * h[(size_t)sq * 64 + lane];
    }
  }
  float r = (acc0 + acc1 + acc2 + acc3) / denom + bias[lane];
  if (do_relu) r = fmaxf(r, 0.f);
  outp[(size_t)n * 64 + lane] = r;
}

// edge scorer in CSR order: one wave per destination node; the v-half (uv[n][64..127])
// is loaded ONCE per node instead of per edge; only the u-gather stays random.
// 4x 16-lane groups each walk the segment stride-4, 2-way unrolled for MLP.
__global__ __launch_bounds__(256) void k_final(const int* __restrict__ offa, const int4* __restrict__ pk,
                                               const float* __restrict__ uv, const float* __restrict__ s1b,
                                               const float* __restrict__ s2w, const float* __restrict__ s2b,
                                               float* __restrict__ outp) {
  int gt = blockIdx.x * 256 + threadIdx.x;
  int n = gt >> 6, lane = gt & 63;
  if (n >= NN) return;
  int g = lane >> 4, i = lane & 15;
  int beg = offa[n], end = offa[n + 1];
  float4 v4 = ((const float4*)(uv + (size_t)n * 128 + 64))[i];
  float4 bb = ((const float4*)s1b)[i];
  float4 ww = ((const float4*)s2w)[i];
  float4 vb = make_float4(v4.x + bb.x, v4.y + bb.y, v4.z + bb.z, v4.w + bb.w);
  float sb = s2b[0];
  int p = beg + g;
  for (; p + 4 < end; p += 8) {
    int4 qa = pk[p];
    int4 qb = pk[p + 4];
    float4 ua = ((const float4*)(uv + (size_t)qa.x * 128))[i];
    float4 ub = ((const float4*)(uv + (size_t)qb.x * 128))[i];
    float za = fmaxf(ua.x + vb.x, 0.f) * ww.x + fmaxf(ua.y + vb.y, 0.f) * ww.y
             + fmaxf(ua.z + vb.z, 0.f) * ww.z + fmaxf(ua.w + vb.w, 0.f) * ww.w;
    float zb = fmaxf(ub.x + vb.x, 0.f) * ww.x + fmaxf(ub.y + vb.y, 0.f) * ww.y
             + fmaxf(ub.z + vb.z, 0.f) * ww.z + fmaxf(ub.w + vb.w, 0.f) * ww.w;
    #pragma unroll
    for (int m = 1; m < 16; m <<= 1) { za += __shfl_xor(za, m, 16); zb += __shfl_xor(zb, m, 16); }
    if (i == 0) {
      outp[qa.w] = 1.f / (1.f + __expf(-(za + sb)));
      outp[qb.w] = 1.f / (1.f + __expf(-(zb + sb)));
    }
  }
  if (p < end) {
    int4 q = pk[p];
    float4 u = ((const float4*)(uv + (size_t)q.x * 128))[i];
    float z = fmaxf(u.x + vb.x, 0.f) * ww.x + fmaxf(u.y + vb.y, 0.f) * ww.y
            + fmaxf(u.z + vb.z, 0.f) * ww.z + fmaxf(u.w + vb.w, 0.f) * ww.w;
    #pragma unroll
    for (int m = 1; m < 16; m <<= 1) z += __shfl_xor(z, m, 16);
    if (i == 0) outp[q.w] = 1.f / (1.f + __expf(-(z + sb)));
  }
}

extern "C" void kernel_launch(void* const* d_in, const int* in_sizes, int n_in,
                              void* d_out, int out_size, void* d_ws, size_t ws_size,
                              hipStream_t stream) {
  const float* x    = (const float*)d_in[0];
  const float* attr = (const float*)d_in[1];
  const int*   eidx = (const int*)d_in[2];   // [2][NE]: row then col
  const float* encW = (const float*)d_in[3];
  const float* encb = (const float*)d_in[4];
  const float* W1   = (const float*)d_in[5];
  const float* le1W = (const float*)d_in[6];
  const float* as1  = (const float*)d_in[7];
  const float* ad1  = (const float*)d_in[8];
  const float* ae1w = (const float*)d_in[9];
  const float* b1   = (const float*)d_in[10];
  const float* W2   = (const float*)d_in[11];
  const float* le2W = (const float*)d_in[12];
  const float* as2  = (const float*)d_in[13];
  const float* ad2  = (const float*)d_in[14];
  const float* ae2w = (const float*)d_in[15];
  const float* b2   = (const float*)d_in[16];
  const float* s1W  = (const float*)d_in[17];
  const float* s1b  = (const float*)d_in[18];
  const float* s2w  = (const float*)d_in[19];
  const float* s2b  = (const float*)d_in[20];
  float* outp = (float*)d_out;

  const int* row = eidx;
  const int* col = eidx + NE;

  char* p = (char*)d_ws;
  auto alloc = [&](size_t bytes) { char* r = p; p += (bytes + 255) & ~(size_t)255; return r; };
  float* small = (float*)alloc(1024);
  unsigned* maxi = (unsigned*)alloc(256);
  float* Scomb = (float*)alloc(8192 * 4);
  int*   counts= (int*)alloc((size_t)NN * 4);
  int*   offa  = (int*)alloc((size_t)(NN + 1) * 4);
  int*   bsums = (int*)alloc((size_t)SCAN_NB * 4);
  float* a_e1  = (float*)alloc((size_t)NE * 4);
  float* a_e2  = (float*)alloc((size_t)NE * 4);
  int*   rank  = (int*)alloc((size_t)NE * 4);
  int4*  pk    = (int4*)alloc((size_t)NE * 16);
  float* h1    = (float*)alloc((size_t)NN * 64 * 4);
  float* out1  = (float*)alloc((size_t)NN * 64 * 4);   // contiguous after h1
  float* h2    = (float*)alloc((size_t)NN * 64 * 4);
  float* out2  = (float*)alloc((size_t)NN * 64 * 4);
  float* asrc1 = (float*)alloc((size_t)NN * 4);
  float* adst1 = (float*)alloc((size_t)NN * 4);
  float* asrc2 = (float*)alloc((size_t)NN * 4);
  float* adst2 = (float*)alloc((size_t)NN * 4);
  float* uv = h1;  // [NN][128], reuses h1||out1 (both dead by then)

  hipMemsetAsync(small, 0, 1024, stream);
  hipMemsetAsync(maxi, 0, 256, stream);
  hipMemsetAsync(counts, 0, (size_t)NN * 4, stream);

  k_small0<<<1, 64, 0, stream>>>(le1W, ae1w, le2W, ae2w, encW, encb, s1W, small, Scomb);
  // fused: edgepre (3125 blocks) + layer-1 GEMM (782 blocks)
  k_fused0<<<EP_NB + GM_NB, 256, 0, stream>>>(attr, col, small, a_e1, a_e2, rank, counts,
                                              small + 228, maxi, x, W1, h1, as1, ad1, asrc1, adst1);
  k_scanA<<<SCAN_NB, 256, 0, stream>>>(counts, offa, bsums);
  k_scanB<<<1, 256, 0, stream>>>(bsums, offa, small);
  k_scanC<<<SCAN_NB, 256, 0, stream>>>(offa, bsums);
  k_scatter<<<(NE / 2 + 255) / 256, 256, 0, stream>>>(row, col, a_e1, a_e2, rank, offa, pk);

  // layer 1 aggregation
  k_agg<<<(NN * 64) / 256, 256, 0, stream>>>(h1, offa, pk, 0, asrc1, adst1,
                                             small, 194, maxi, b1, out1, 1);
  // layer 2
  k_gemm<64, 1><<<dim3((NN + 63) / 64, 1), 256, 0, stream>>>(out1, W2, h2, NN, 64, as2, ad2, asrc2, adst2, maxi + 1);
  k_agg<<<(NN * 64) / 256, 256, 0, stream>>>(h2, offa, pk, 1, asrc2, adst2,
                                             small, 195, maxi, b2, out2, 0);
  // scorer: uv = [u | v]
  k_gemm<64, 0><<<dim3((NN + 63) / 64, 2), 256, 0, stream>>>(out2, Scomb, uv, NN, 128, nullptr, nullptr, nullptr, nullptr, nullptr);
  k_final<<<(NN * 64) / 256, 256, 0, stream>>>(offa, pk, uv, s1b, s2w, s2b, outp);
}

// Round 14
// 301.812 us; speedup vs baseline: 1.3448x; 1.0071x over previous
//
#include <hip/hip_runtime.h>
#include <cstdint>
#include <cstddef>

#define NN 50000
#define NE 800000
#define FN 128
#define FE 32
#define HD 64
#define SCAN_NB ((NN + 255) / 256)   // 196
#define EP_NB (NE / 256)             // 3125 edgepre blocks
#define GM_NB ((NN + 63) / 64)       // 782 gemm blocks

__device__ __forceinline__ float lrelu(float x) { return x > 0.f ? x : 0.2f * x; }

// order-preserving float<->uint map for atomicMax on floats (0 == -inf sentinel)
__device__ __forceinline__ unsigned omap(float f) {
  unsigned u = __float_as_uint(f);
  return (u & 0x80000000u) ? ~u : (u | 0x80000000u);
}
__device__ __forceinline__ float odec(unsigned u) {
  return __uint_as_float((u & 0x80000000u) ? (u ^ 0x80000000u) : ~u);
}

// small[] layout (floats): 0..63 vec1 | 64..127 vec2 | 128..159 p1 | 160..191 p2
// 192 c1 | 193 c2 | 194 a_self1 | 195 a_self2 | 228 sum_d1 | 229 sum_d2
// maxi[] (uint): 0 Mas1 | 1 Mas2 | 2 Mae1 | 3 Mae2
// block 0: small-param precompute; blocks 1..SCAN_NB: zero counts (fused memset)
__global__ __launch_bounds__(256) void k_small0(const float* __restrict__ le1W, const float* __restrict__ ae1,
                         const float* __restrict__ le2W, const float* __restrict__ ae2,
                         const float* __restrict__ encW, const float* __restrict__ encb,
                         const float* __restrict__ s1W,
                         float* __restrict__ small, float* __restrict__ Scomb,
                         int* __restrict__ counts) {
  int t = threadIdx.x;
  if (blockIdx.x > 0) {
    int i = (blockIdx.x - 1) * 256 + t;
    if (i < NN) counts[i] = 0;
    return;
  }
  __shared__ float sv1[64], sv2[64];
  if (t < 64) {
    float v1 = 0.f, v2 = 0.f;
    for (int j = 0; j < 64; ++j) {
      v1 += le1W[j * 64 + t] * ae1[j];
      v2 += le2W[j * 64 + t] * ae2[j];
    }
    sv1[t] = v1; sv2[t] = v2;
    small[t] = v1; small[64 + t] = v2;
    float cb1 = encb[t] * v1, cb2 = encb[t] * v2;
    #pragma unroll
    for (int m = 32; m; m >>= 1) { cb1 += __shfl_xor(cb1, m); cb2 += __shfl_xor(cb2, m); }
    if (t == 0) { small[192] = cb1; small[193] = cb2; }
  }
  __syncthreads();
  if (t < 32) {
    float p1 = 0.f, p2 = 0.f;
    for (int i = 0; i < 64; ++i) {
      p1 += encW[i * 32 + t] * sv1[i];
      p2 += encW[i * 32 + t] * sv2[i];
    }
    small[128 + t] = p1; small[160 + t] = p2;
  }
  if (t < 64) {
    for (int j = 0; j < 64; ++j) {
      Scomb[j * 64 + t] = s1W[j * 128 + t];
      Scomb[(64 + j) * 64 + t] = s1W[j * 128 + 64 + t];
    }
  }
}

// hierarchical exclusive scan of counts -> offa, offa[NN]=NE
__global__ __launch_bounds__(256) void k_scanA(const int* __restrict__ counts,
                                               int* __restrict__ loc, int* __restrict__ blocksums) {
  int tid = threadIdx.x;
  int i = blockIdx.x * 256 + tid;
  int v = (i < NN) ? counts[i] : 0;
  int lane = tid & 63, wid = tid >> 6;
  int x = v;
  #pragma unroll
  for (int d = 1; d < 64; d <<= 1) {
    int y = __shfl_up(x, d);
    if (lane >= d) x += y;
  }
  __shared__ int ws[4], wpref[4];
  if (lane == 63) ws[wid] = x;
  __syncthreads();
  if (tid == 0) {
    int run = 0;
    #pragma unroll
    for (int w = 0; w < 4; ++w) { wpref[w] = run; run += ws[w]; }
    blocksums[blockIdx.x] = run;
  }
  __syncthreads();
  if (i < NN) loc[i] = x - v + wpref[wid];
}

// also finalizes the self-loop scalars
__global__ __launch_bounds__(256) void k_scanB(int* __restrict__ blocksums, int* __restrict__ offa,
                                               float* __restrict__ small) {
  int tid = threadIdx.x;
  int v = (tid < SCAN_NB) ? blocksums[tid] : 0;
  int lane = tid & 63, wid = tid >> 6;
  int x = v;
  #pragma unroll
  for (int d = 1; d < 64; d <<= 1) {
    int y = __shfl_up(x, d);
    if (lane >= d) x += y;
  }
  __shared__ int ws[4], wpref[4];
  if (lane == 63) ws[wid] = x;
  __syncthreads();
  if (tid == 0) {
    int run = 0;
    #pragma unroll
    for (int w = 0; w < 4; ++w) { wpref[w] = run; run += ws[w]; }
    offa[NN] = run;   // == NE
    small[194] = small[228] * (1.0f / NE);
    small[195] = small[229] * (1.0f / NE);
  }
  __syncthreads();
  if (tid < SCAN_NB) blocksums[tid] = x - v + wpref[wid];
}

__global__ __launch_bounds__(256) void k_scanC(int* __restrict__ offa, const int* __restrict__ blocksums) {
  int i = blockIdx.x * 256 + threadIdx.x;
  if (i < NN) offa[i] = offa[i] + blocksums[blockIdx.x];
}

// FUSED: blocks [0, EP_NB) run edgepre (LDS-staged attr dots, rank atomic, sums/maxes);
// blocks [EP_NB, EP_NB+GM_NB) run the independent layer-1 GEMM h1 = x @ W1^T (+ asd epilogue).
__global__ __launch_bounds__(256) void k_fused0(const float* __restrict__ attr,
                                                const int* __restrict__ col,
                                                const float* __restrict__ small,
                                                float* __restrict__ a_e1, float* __restrict__ a_e2,
                                                int* __restrict__ rank,
                                                int* __restrict__ counts,
                                                float* __restrict__ sums,
                                                unsigned* __restrict__ maxi,
                                                const float* __restrict__ x, const float* __restrict__ W1,
                                                float* __restrict__ h1,
                                                const float* __restrict__ as, const float* __restrict__ ad,
                                                float* __restrict__ asrc, float* __restrict__ adst) {
  __shared__ float smem[8704];   // edgepre: 8448 sattr + 16 redbuf | gemm: 2x 64x68 tiles
  int tid = threadIdx.x;
  if (blockIdx.x < EP_NB) {
    float* sattr = smem;
    float* redbuf = smem + 8448;
    float sp1[32], sp2[32];
    #pragma unroll
    for (int j = 0; j < 8; ++j) {
      float4 v1 = ((const float4*)(small + 128))[j];
      float4 v2 = ((const float4*)(small + 160))[j];
      sp1[j*4+0] = v1.x; sp1[j*4+1] = v1.y; sp1[j*4+2] = v1.z; sp1[j*4+3] = v1.w;
      sp2[j*4+0] = v2.x; sp2[j*4+1] = v2.y; sp2[j*4+2] = v2.z; sp2[j*4+3] = v2.w;
    }
    float c1 = small[192], c2 = small[193];
    int e = blockIdx.x * 256 + tid;
    int c = col[e];   // issue early
    const float4* ain = (const float4*)(attr + (size_t)blockIdx.x * 256 * FE);
    #pragma unroll
    for (int it = 0; it < 8; ++it) {
      int idx = it * 256 + tid;
      float4 v = ain[idx];
      int r = idx >> 3, ch = idx & 7;
      float* dst = &sattr[r * 33 + ch * 4];
      dst[0] = v.x; dst[1] = v.y; dst[2] = v.z; dst[3] = v.w;
    }
    __syncthreads();
    const float* myrow = &sattr[tid * 33];
    float d1 = c1, d2 = c2;
    #pragma unroll
    for (int j = 0; j < 32; ++j) {
      float a = myrow[j];
      d1 += a * sp1[j];
      d2 += a * sp2[j];
    }
    a_e1[e] = d1;
    a_e2[e] = d2;
    rank[e] = atomicAdd(&counts[c], 1);
    float s1 = d1, s2 = d2, m1 = d1, m2 = d2;
    #pragma unroll
    for (int m = 32; m; m >>= 1) {
      s1 += __shfl_xor(s1, m); s2 += __shfl_xor(s2, m);
      m1 = fmaxf(m1, __shfl_xor(m1, m)); m2 = fmaxf(m2, __shfl_xor(m2, m));
    }
    int wid = tid >> 6;
    if ((tid & 63) == 0) { redbuf[wid] = s1; redbuf[4 + wid] = s2; redbuf[8 + wid] = m1; redbuf[12 + wid] = m2; }
    __syncthreads();
    if (tid == 0) atomicAdd(&sums[0], redbuf[0] + redbuf[1] + redbuf[2] + redbuf[3]);
    if (tid == 1) atomicAdd(&sums[1], redbuf[4] + redbuf[5] + redbuf[6] + redbuf[7]);
    if (tid == 2) atomicMax(&maxi[2], omap(fmaxf(fmaxf(redbuf[8], redbuf[9]), fmaxf(redbuf[10], redbuf[11]))));
    if (tid == 3) atomicMax(&maxi[3], omap(fmaxf(fmaxf(redbuf[12], redbuf[13]), fmaxf(redbuf[14], redbuf[15]))));
  } else {
    // layer-1 GEMM: h1[NN][64] = x[NN][128] @ W1[64][128]^T, asd epilogue -> asrc/adst/maxi[0]
    float (*At)[68] = (float(*)[68])smem;
    float (*Bt)[68] = (float(*)[68])(smem + 4352);
    int m0 = (blockIdx.x - EP_NB) * 64;
    float acc[4][4] = {};
    for (int kc = 0; kc < 128; kc += 64) {
      #pragma unroll
      for (int it = 0; it < 4; ++it) {
        int idx = it * 256 + tid;
        int m = idx & 63, kv = idx >> 6;
        float4 bv = ((const float4*)(W1 + (size_t)m * 128 + kc))[kv];
        Bt[kv*4+0][m] = bv.x; Bt[kv*4+1][m] = bv.y; Bt[kv*4+2][m] = bv.z; Bt[kv*4+3][m] = bv.w;
        int gm = m0 + m;
        float4 av = make_float4(0.f, 0.f, 0.f, 0.f);
        if (gm < NN) av = ((const float4*)(x + (size_t)gm * 128 + kc))[kv];
        At[kv*4+0][m] = av.x; At[kv*4+1][m] = av.y; At[kv*4+2][m] = av.z; At[kv*4+3][m] = av.w;
      }
      __syncthreads();
      int tn = tid & 15, tm = tid >> 4;
      #pragma unroll 8
      for (int k = 0; k < 64; ++k) {
        float4 a4 = *(const float4*)&At[k][tm * 4];
        float4 b4 = *(const float4*)&Bt[k][tn * 4];
        acc[0][0] += a4.x*b4.x; acc[0][1] += a4.x*b4.y; acc[0][2] += a4.x*b4.z; acc[0][3] += a4.x*b4.w;
        acc[1][0] += a4.y*b4.x; acc[1][1] += a4.y*b4.y; acc[1][2] += a4.y*b4.z; acc[1][3] += a4.y*b4.w;
        acc[2][0] += a4.z*b4.x; acc[2][1] += a4.z*b4.y; acc[2][2] += a4.z*b4.z; acc[2][3] += a4.z*b4.w;
        acc[3][0] += a4.w*b4.x; acc[3][1] += a4.w*b4.y; acc[3][2] += a4.w*b4.z; acc[3][3] += a4.w*b4.w;
      }
      __syncthreads();
    }
    int tn = tid & 15, tm = tid >> 4;
    #pragma unroll
    for (int i = 0; i < 4; ++i) {
      int gm = m0 + tm * 4 + i;
      if (gm < NN) {
        float4 o = make_float4(acc[i][0], acc[i][1], acc[i][2], acc[i][3]);
        *(float4*)(h1 + (size_t)gm * 64 + tn * 4) = o;
      }
    }
    __shared__ float wmax[4];
    float4 asv = ((const float4*)as)[tn];
    float4 adv = ((const float4*)ad)[tn];
    float smax = -1e30f;
    #pragma unroll
    for (int i = 0; i < 4; ++i) {
      float s = acc[i][0]*asv.x + acc[i][1]*asv.y + acc[i][2]*asv.z + acc[i][3]*asv.w;
      float d = acc[i][0]*adv.x + acc[i][1]*adv.y + acc[i][2]*adv.z + acc[i][3]*adv.w;
      #pragma unroll
      for (int m = 8; m; m >>= 1) { s += __shfl_xor(s, m, 16); d += __shfl_xor(d, m, 16); }
      int gm = m0 + tm * 4 + i;
      if (tn == 0 && gm < NN) { asrc[gm] = s; adst[gm] = d; smax = fmaxf(smax, s); }
    }
    #pragma unroll
    for (int m = 32; m; m >>= 1) smax = fmaxf(smax, __shfl_xor(smax, m));
    if ((tid & 63) == 0) wmax[tid >> 6] = smax;
    __syncthreads();
    if (tid == 0)
      atomicMax(&maxi[0], omap(fmaxf(fmaxf(wmax[0], wmax[1]), fmaxf(wmax[2], wmax[3]))));
  }
}

// atomic-free scatter, 4 independent edge-chains per thread (MLP), guarded tail.
// pk[p] = {src, ae1_bits, ae2_bits, eid} — eid enables CSR-order k_final.
__global__ __launch_bounds__(256) void k_scatter(const int* __restrict__ row, const int* __restrict__ col,
                                                 const float* __restrict__ a_e1, const float* __restrict__ a_e2,
                                                 const int* __restrict__ rank, const int* __restrict__ offa,
                                                 int4* __restrict__ pk) {
  int t = blockIdx.x * 256 + threadIdx.x;
  if (t >= NE / 4) return;
  int e0 = t, e1 = t + NE / 4, e2 = t + NE / 2, e3 = t + 3 * (NE / 4);
  int c0 = col[e0], c1 = col[e1], c2 = col[e2], c3 = col[e3];
  int r0 = rank[e0], r1 = rank[e1], r2 = rank[e2], r3 = rank[e3];
  int o0 = offa[c0], o1 = offa[c1], o2 = offa[c2], o3 = offa[c3];
  int4 q0, q1, q2, q3;
  q0.x = row[e0]; q0.y = __float_as_int(a_e1[e0]); q0.z = __float_as_int(a_e2[e0]); q0.w = e0;
  q1.x = row[e1]; q1.y = __float_as_int(a_e1[e1]); q1.z = __float_as_int(a_e2[e1]); q1.w = e1;
  q2.x = row[e2]; q2.y = __float_as_int(a_e1[e2]); q2.z = __float_as_int(a_e2[e2]); q2.w = e2;
  q3.x = row[e3]; q3.y = __float_as_int(a_e1[e3]); q3.z = __float_as_int(a_e2[e3]); q3.w = e3;
  pk[o0 + r0] = q0;
  pk[o1 + r1] = q1;
  pk[o2 + r2] = q2;
  pk[o3 + r3] = q3;
}

// C[M][ldc-tile] = A[M][K] * B^T, B is [64][K] row-major (per blockIdx.y tile)
// ASD: also emit asrc/adst from the accumulator tile + global max(asrc) -> maxslot
template <int K, int ASD>
__global__ __launch_bounds__(256) void k_gemm(const float* __restrict__ A, const float* __restrict__ B,
                                              float* __restrict__ C, int M, int ldc,
                                              const float* __restrict__ as, const float* __restrict__ ad,
                                              float* __restrict__ asrc, float* __restrict__ adst,
                                              unsigned* __restrict__ maxslot) {
  __shared__ float At[64][68];
  __shared__ float Bt[64][68];
  int tid = threadIdx.x;
  int m0 = blockIdx.x * 64;
  const float* Bp = B + (size_t)blockIdx.y * 64 * K;
  float acc[4][4] = {};
  for (int kc = 0; kc < K; kc += 64) {
    #pragma unroll
    for (int it = 0; it < 4; ++it) {
      int idx = it * 256 + tid;
      int m = idx & 63, kv = idx >> 6;  // kv in 0..15
      float4 bv = ((const float4*)(Bp + (size_t)m * K + kc))[kv];
      Bt[kv*4+0][m] = bv.x; Bt[kv*4+1][m] = bv.y; Bt[kv*4+2][m] = bv.z; Bt[kv*4+3][m] = bv.w;
      int gm = m0 + m;
      float4 av = make_float4(0.f, 0.f, 0.f, 0.f);
      if (gm < M) av = ((const float4*)(A + (size_t)gm * K + kc))[kv];
      At[kv*4+0][m] = av.x; At[kv*4+1][m] = av.y; At[kv*4+2][m] = av.z; At[kv*4+3][m] = av.w;
    }
    __syncthreads();
    int tn = tid & 15, tm = tid >> 4;
    #pragma unroll 8
    for (int k = 0; k < 64; ++k) {
      float4 a4 = *(const float4*)&At[k][tm * 4];
      float4 b4 = *(const float4*)&Bt[k][tn * 4];
      acc[0][0] += a4.x*b4.x; acc[0][1] += a4.x*b4.y; acc[0][2] += a4.x*b4.z; acc[0][3] += a4.x*b4.w;
      acc[1][0] += a4.y*b4.x; acc[1][1] += a4.y*b4.y; acc[1][2] += a4.y*b4.z; acc[1][3] += a4.y*b4.w;
      acc[2][0] += a4.z*b4.x; acc[2][1] += a4.z*b4.y; acc[2][2] += a4.z*b4.z; acc[2][3] += a4.z*b4.w;
      acc[3][0] += a4.w*b4.x; acc[3][1] += a4.w*b4.y; acc[3][2] += a4.w*b4.z; acc[3][3] += a4.w*b4.w;
    }
    __syncthreads();
  }
  int tn = tid & 15, tm = tid >> 4;
  #pragma unroll
  for (int i = 0; i < 4; ++i) {
    int gm = m0 + tm * 4 + i;
    if (gm < M) {
      float4 o = make_float4(acc[i][0], acc[i][1], acc[i][2], acc[i][3]);
      *(float4*)(C + (size_t)gm * ldc + blockIdx.y * 64 + tn * 4) = o;
    }
  }
  if constexpr (ASD) {
    __shared__ float wmax[4];
    float4 asv = ((const float4*)as)[tn];
    float4 adv = ((const float4*)ad)[tn];
    float smax = -1e30f;
    #pragma unroll
    for (int i = 0; i < 4; ++i) {
      float s = acc[i][0]*asv.x + acc[i][1]*asv.y + acc[i][2]*asv.z + acc[i][3]*asv.w;
      float d = acc[i][0]*adv.x + acc[i][1]*adv.y + acc[i][2]*adv.z + acc[i][3]*adv.w;
      #pragma unroll
      for (int m = 8; m; m >>= 1) { s += __shfl_xor(s, m, 16); d += __shfl_xor(d, m, 16); }
      int gm = m0 + tm * 4 + i;
      if (tn == 0 && gm < M) { asrc[gm] = s; adst[gm] = d; smax = fmaxf(smax, s); }
    }
    #pragma unroll
    for (int m = 32; m; m >>= 1) smax = fmaxf(smax, __shfl_xor(smax, m));
    if ((tid & 63) == 0) wmax[tid >> 6] = smax;
    __syncthreads();
    if (tid == 0)
      atomicMax(maxslot, omap(fmaxf(fmaxf(wmax[0], wmax[1]), fmaxf(wmax[2], wmax[3]))));
  }
}

// one wave per destination node, SINGLE PASS softmax (global-bound shift),
// 8-way unrolled gather loop with independent accumulators (MLP for load latency).
__global__ __launch_bounds__(256) void k_agg(const float* __restrict__ h, const int* __restrict__ offa,
                                             const int4* __restrict__ pk, int comp,
                                             const float* __restrict__ asrc, const float* __restrict__ adst,
                                             const float* __restrict__ small, int selfIdx,
                                             const unsigned* __restrict__ maxi,
                                             const float* __restrict__ bias, float* __restrict__ outp,
                                             int do_relu) {
  int gt = blockIdx.x * 256 + threadIdx.x;
  int n = gt >> 6, lane = gt & 63;
  if (n >= NN) return;
  int beg = offa[n], end = offa[n + 1];
  float adn = adst[n];
  // shift bound: m >= every alpha in this segment (softmax is shift-invariant)
  float mx = lrelu(odec(maxi[comp]) + adn + odec(maxi[2 + comp]));
  float alpha_self = lrelu(asrc[n] + adn + small[selfIdx]);
  float ex_self = __expf(alpha_self - mx);
  float denom = ex_self;
  float acc0 = ex_self * h[(size_t)n * 64 + lane];
  float acc1 = 0.f, acc2 = 0.f, acc3 = 0.f;
  float acc4 = 0.f, acc5 = 0.f, acc6 = 0.f, acc7 = 0.f;
  for (int base = beg; base < end; base += 64) {
    int p = base + lane;
    int cnt = min(64, end - base);
    float ex = 0.f; int s = 0;
    if (p < end) {
      int4 q = pk[p];
      s = q.x;
      float ae = __int_as_float(comp ? q.z : q.y);
      ex = __expf(lrelu(asrc[s] + adn + ae) - mx);
    }
    float exs = ex;
    #pragma unroll
    for (int m = 32; m; m >>= 1) exs += __shfl_xor(exs, m);
    denom += exs;
    int q8 = cnt & ~7;
    int q = 0;
    for (; q < q8; q += 8) {
      float e0 = __shfl(ex, q),     e1 = __shfl(ex, q + 1);
      float e2 = __shfl(ex, q + 2), e3 = __shfl(ex, q + 3);
      float e4 = __shfl(ex, q + 4), e5 = __shfl(ex, q + 5);
      float e6 = __shfl(ex, q + 6), e7 = __shfl(ex, q + 7);
      int s0 = __shfl(s, q),     s1 = __shfl(s, q + 1);
      int s2 = __shfl(s, q + 2), s3 = __shfl(s, q + 3);
      int s4 = __shfl(s, q + 4), s5 = __shfl(s, q + 5);
      int s6 = __shfl(s, q + 6), s7 = __shfl(s, q + 7);
      acc0 += e0 * h[(size_t)s0 * 64 + lane];
      acc1 += e1 * h[(size_t)s1 * 64 + lane];
      acc2 += e2 * h[(size_t)s2 * 64 + lane];
      acc3 += e3 * h[(size_t)s3 * 64 + lane];
      acc4 += e4 * h[(size_t)s4 * 64 + lane];
      acc5 += e5 * h[(size_t)s5 * 64 + lane];
      acc6 += e6 * h[(size_t)s6 * 64 + lane];
      acc7 += e7 * h[(size_t)s7 * 64 + lane];
    }
    int q4 = cnt & ~3;
    if (q < q4) {
      float e0 = __shfl(ex, q),     e1 = __shfl(ex, q + 1);
      float e2 = __shfl(ex, q + 2), e3 = __shfl(ex, q + 3);
      int s0 = __shfl(s, q),     s1 = __shfl(s, q + 1);
      int s2 = __shfl(s, q + 2), s3 = __shfl(s, q + 3);
      acc0 += e0 * h[(size_t)s0 * 64 + lane];
      acc1 += e1 * h[(size_t)s1 * 64 + lane];
      acc2 += e2 * h[(size_t)s2 * 64 + lane];
      acc3 += e3 * h[(size_t)s3 * 64 + lane];
      q = q4;
    }
    for (; q < cnt; ++q) {
      float eq = __shfl(ex, q);
      int sq = __shfl(s, q);
      acc0 += eq * h[(size_t)sq * 64 + lane];
    }
  }
  float r = ((acc0 + acc1) + (acc2 + acc3)) + ((acc4 + acc5) + (acc6 + acc7));
  r = r / denom + bias[lane];
  if (do_relu) r = fmaxf(r, 0.f);
  outp[(size_t)n * 64 + lane] = r;
}

// edge scorer in CSR order: one wave per destination node; the v-half (uv[n][64..127])
// is loaded ONCE per node instead of per edge; only the u-gather stays random.
// 4x 16-lane groups each walk the segment stride-4, 2-way unrolled for MLP.
__global__ __launch_bounds__(256) void k_final(const int* __restrict__ offa, const int4* __restrict__ pk,
                                               const float* __restrict__ uv, const float* __restrict__ s1b,
                                               const float* __restrict__ s2w, const float* __restrict__ s2b,
                                               float* __restrict__ outp) {
  int gt = blockIdx.x * 256 + threadIdx.x;
  int n = gt >> 6, lane = gt & 63;
  if (n >= NN) return;
  int g = lane >> 4, i = lane & 15;
  int beg = offa[n], end = offa[n + 1];
  float4 v4 = ((const float4*)(uv + (size_t)n * 128 + 64))[i];
  float4 bb = ((const float4*)s1b)[i];
  float4 ww = ((const float4*)s2w)[i];
  float4 vb = make_float4(v4.x + bb.x, v4.y + bb.y, v4.z + bb.z, v4.w + bb.w);
  float sb = s2b[0];
  int p = beg + g;
  for (; p + 4 < end; p += 8) {
    int4 qa = pk[p];
    int4 qb = pk[p + 4];
    float4 ua = ((const float4*)(uv + (size_t)qa.x * 128))[i];
    float4 ub = ((const float4*)(uv + (size_t)qb.x * 128))[i];
    float za = fmaxf(ua.x + vb.x, 0.f) * ww.x + fmaxf(ua.y + vb.y, 0.f) * ww.y
             + fmaxf(ua.z + vb.z, 0.f) * ww.z + fmaxf(ua.w + vb.w, 0.f) * ww.w;
    float zb = fmaxf(ub.x + vb.x, 0.f) * ww.x + fmaxf(ub.y + vb.y, 0.f) * ww.y
             + fmaxf(ub.z + vb.z, 0.f) * ww.z + fmaxf(ub.w + vb.w, 0.f) * ww.w;
    #pragma unroll
    for (int m = 1; m < 16; m <<= 1) { za += __shfl_xor(za, m, 16); zb += __shfl_xor(zb, m, 16); }
    if (i == 0) {
      outp[qa.w] = 1.f / (1.f + __expf(-(za + sb)));
      outp[qb.w] = 1.f / (1.f + __expf(-(zb + sb)));
    }
  }
  if (p < end) {
    int4 q = pk[p];
    float4 u = ((const float4*)(uv + (size_t)q.x * 128))[i];
    float z = fmaxf(u.x + vb.x, 0.f) * ww.x + fmaxf(u.y + vb.y, 0.f) * ww.y
            + fmaxf(u.z + vb.z, 0.f) * ww.z + fmaxf(u.w + vb.w, 0.f) * ww.w;
    #pragma unroll
    for (int m = 1; m < 16; m <<= 1) z += __shfl_xor(z, m, 16);
    if (i == 0) outp[q.w] = 1.f / (1.f + __expf(-(z + sb)));
  }
}

extern "C" void kernel_launch(void* const* d_in, const int* in_sizes, int n_in,
                              void* d_out, int out_size, void* d_ws, size_t ws_size,
                              hipStream_t stream) {
  const float* x    = (const float*)d_in[0];
  const float* attr = (const float*)d_in[1];
  const int*   eidx = (const int*)d_in[2];   // [2][NE]: row then col
  const float* encW = (const float*)d_in[3];
  const float* encb = (const float*)d_in[4];
  const float* W1   = (const float*)d_in[5];
  const float* le1W = (const float*)d_in[6];
  const float* as1  = (const float*)d_in[7];
  const float* ad1  = (const float*)d_in[8];
  const float* ae1w = (const float*)d_in[9];
  const float* b1   = (const float*)d_in[10];
  const float* W2   = (const float*)d_in[11];
  const float* le2W = (const float*)d_in[12];
  const float* as2  = (const float*)d_in[13];
  const float* ad2  = (const float*)d_in[14];
  const float* ae2w = (const float*)d_in[15];
  const float* b2   = (const float*)d_in[16];
  const float* s1W  = (const float*)d_in[17];
  const float* s1b  = (const float*)d_in[18];
  const float* s2w  = (const float*)d_in[19];
  const float* s2b  = (const float*)d_in[20];
  float* outp = (float*)d_out;

  const int* row = eidx;
  const int* col = eidx + NE;

  char* p = (char*)d_ws;
  auto alloc = [&](size_t bytes) { char* r = p; p += (bytes + 255) & ~(size_t)255; return r; };
  float* small = (float*)alloc(1024);
  unsigned* maxi = (unsigned*)alloc(256);
  float* Scomb = (float*)alloc(8192 * 4);
  int*   counts= (int*)alloc((size_t)NN * 4);
  int*   offa  = (int*)alloc((size_t)(NN + 1) * 4);
  int*   bsums = (int*)alloc((size_t)SCAN_NB * 4);
  float* a_e1  = (float*)alloc((size_t)NE * 4);
  float* a_e2  = (float*)alloc((size_t)NE * 4);
  int*   rank  = (int*)alloc((size_t)NE * 4);
  int4*  pk    = (int4*)alloc((size_t)NE * 16);
  float* h1    = (float*)alloc((size_t)NN * 64 * 4);
  float* out1  = (float*)alloc((size_t)NN * 64 * 4);   // contiguous after h1
  float* h2    = (float*)alloc((size_t)NN * 64 * 4);
  float* out2  = (float*)alloc((size_t)NN * 64 * 4);
  float* asrc1 = (float*)alloc((size_t)NN * 4);
  float* adst1 = (float*)alloc((size_t)NN * 4);
  float* asrc2 = (float*)alloc((size_t)NN * 4);
  float* adst2 = (float*)alloc((size_t)NN * 4);
  float* uv = h1;  // [NN][128], reuses h1||out1 (both dead by then)

  // small (1024B) and maxi (256B) are adjacent in d_ws: one memset covers both
  hipMemsetAsync(small, 0, 1280, stream);

  // block 0: small-param precompute; blocks 1..196: zero counts
  k_small0<<<SCAN_NB + 1, 256, 0, stream>>>(le1W, ae1w, le2W, ae2w, encW, encb, s1W, small, Scomb, counts);
  // fused: edgepre (3125 blocks) + layer-1 GEMM (782 blocks)
  k_fused0<<<EP_NB + GM_NB, 256, 0, stream>>>(attr, col, small, a_e1, a_e2, rank, counts,
                                              small + 228, maxi, x, W1, h1, as1, ad1, asrc1, adst1);
  k_scanA<<<SCAN_NB, 256, 0, stream>>>(counts, offa, bsums);
  k_scanB<<<1, 256, 0, stream>>>(bsums, offa, small);
  k_scanC<<<SCAN_NB, 256, 0, stream>>>(offa, bsums);
  k_scatter<<<(NE / 4 + 255) / 256, 256, 0, stream>>>(row, col, a_e1, a_e2, rank, offa, pk);

  // layer 1 aggregation
  k_agg<<<(NN * 64) / 256, 256, 0, stream>>>(h1, offa, pk, 0, asrc1, adst1,
                                             small, 194, maxi, b1, out1, 1);
  // layer 2
  k_gemm<64, 1><<<dim3((NN + 63) / 64, 1), 256, 0, stream>>>(out1, W2, h2, NN, 64, as2, ad2, asrc2, adst2, maxi + 1);
  k_agg<<<(NN * 64) / 256, 256, 0, stream>>>(h2, offa, pk, 1, asrc2, adst2,
                                             small, 195, maxi, b2, out2, 0);
  // scorer: uv = [u | v]
  k_gemm<64, 0><<<dim3((NN + 63) / 64, 2), 256, 0, stream>>>(out2, Scomb, uv, NN, 128, nullptr, nullptr, nullptr, nullptr, nullptr);
  k_final<<<(NN * 64) / 256, 256, 0, stream>>>(offa, pk, uv, s1b, s2w, s2b, outp);
}

// Round 15
// 300.483 us; speedup vs baseline: 1.3507x; 1.0044x over previous
//
#include <hip/hip_runtime.h>
#include <cstdint>
#include <cstddef>

#define NN 50000
#define NE 800000
#define FN 128
#define FE 32
#define HD 64
#define SCAN_NB ((NN + 255) / 256)   // 196
#define EP_NB (NE / 256)             // 3125 edgepre blocks
#define GM_NB ((NN + 63) / 64)       // 782 gemm blocks

typedef float vfloat4 __attribute__((ext_vector_type(4)));

__device__ __forceinline__ float lrelu(float x) { return x > 0.f ? x : 0.2f * x; }

// order-preserving float<->uint map for atomicMax on floats (0 == -inf sentinel)
__device__ __forceinline__ unsigned omap(float f) {
  unsigned u = __float_as_uint(f);
  return (u & 0x80000000u) ? ~u : (u | 0x80000000u);
}
__device__ __forceinline__ float odec(unsigned u) {
  return __uint_as_float((u & 0x80000000u) ? (u ^ 0x80000000u) : ~u);
}

// small[] layout (floats): 0..63 vec1 | 64..127 vec2 | 128..159 p1 | 160..191 p2
// 192 c1 | 193 c2 | 194 a_self1 | 195 a_self2 | 228 sum_d1 | 229 sum_d2
// maxi[] (uint): 0 Mas1 | 1 Mas2 | 2 Mae1 | 3 Mae2
// block 0: small-param precompute; blocks 1..SCAN_NB: zero counts (fused memset)
__global__ __launch_bounds__(256) void k_small0(const float* __restrict__ le1W, const float* __restrict__ ae1,
                         const float* __restrict__ le2W, const float* __restrict__ ae2,
                         const float* __restrict__ encW, const float* __restrict__ encb,
                         const float* __restrict__ s1W,
                         float* __restrict__ small, float* __restrict__ Scomb,
                         int* __restrict__ counts) {
  int t = threadIdx.x;
  if (blockIdx.x > 0) {
    int i = (blockIdx.x - 1) * 256 + t;
    if (i < NN) counts[i] = 0;
    return;
  }
  __shared__ float sv1[64], sv2[64];
  if (t < 64) {
    float v1 = 0.f, v2 = 0.f;
    for (int j = 0; j < 64; ++j) {
      v1 += le1W[j * 64 + t] * ae1[j];
      v2 += le2W[j * 64 + t] * ae2[j];
    }
    sv1[t] = v1; sv2[t] = v2;
    small[t] = v1; small[64 + t] = v2;
    float cb1 = encb[t] * v1, cb2 = encb[t] * v2;
    #pragma unroll
    for (int m = 32; m; m >>= 1) { cb1 += __shfl_xor(cb1, m); cb2 += __shfl_xor(cb2, m); }
    if (t == 0) { small[192] = cb1; small[193] = cb2; }
  }
  __syncthreads();
  if (t < 32) {
    float p1 = 0.f, p2 = 0.f;
    for (int i = 0; i < 64; ++i) {
      p1 += encW[i * 32 + t] * sv1[i];
      p2 += encW[i * 32 + t] * sv2[i];
    }
    small[128 + t] = p1; small[160 + t] = p2;
  }
  if (t < 64) {
    for (int j = 0; j < 64; ++j) {
      Scomb[j * 64 + t] = s1W[j * 128 + t];
      Scomb[(64 + j) * 64 + t] = s1W[j * 128 + 64 + t];
    }
  }
}

// hierarchical exclusive scan of counts -> loc(in offa) + blocksums
__global__ __launch_bounds__(256) void k_scanA(const int* __restrict__ counts,
                                               int* __restrict__ loc, int* __restrict__ blocksums) {
  int tid = threadIdx.x;
  int i = blockIdx.x * 256 + tid;
  int v = (i < NN) ? counts[i] : 0;
  int lane = tid & 63, wid = tid >> 6;
  int x = v;
  #pragma unroll
  for (int d = 1; d < 64; d <<= 1) {
    int y = __shfl_up(x, d);
    if (lane >= d) x += y;
  }
  __shared__ int ws[4], wpref[4];
  if (lane == 63) ws[wid] = x;
  __syncthreads();
  if (tid == 0) {
    int run = 0;
    #pragma unroll
    for (int w = 0; w < 4; ++w) { wpref[w] = run; run += ws[w]; }
    blocksums[blockIdx.x] = run;
  }
  __syncthreads();
  if (i < NN) loc[i] = x - v + wpref[wid];
}

// merged scanB+scanC: each block redundantly computes its prefix over the 196
// raw block sums (cheap), adds it to its offa range; block 0 finalizes
// offa[NN] and the self-loop scalars.
__global__ __launch_bounds__(256) void k_scanBC(const int* __restrict__ blocksums,
                                                int* __restrict__ offa,
                                                float* __restrict__ small) {
  __shared__ int sb[SCAN_NB];
  int tid = threadIdx.x;
  if (tid < SCAN_NB) sb[tid] = blocksums[tid];
  __syncthreads();
  int pre = 0;
  for (int b = 0; b < blockIdx.x; ++b) pre += sb[b];
  int i = blockIdx.x * 256 + tid;
  if (i < NN) offa[i] += pre;
  if (blockIdx.x == 0 && tid == 0) {
    int tot = 0;
    for (int b = 0; b < SCAN_NB; ++b) tot += sb[b];
    offa[NN] = tot;   // == NE
    small[194] = small[228] * (1.0f / NE);
    small[195] = small[229] * (1.0f / NE);
  }
}

// FUSED: blocks [0, EP_NB) run edgepre (LDS-staged attr dots, rank atomic, sums/maxes);
// blocks [EP_NB, EP_NB+GM_NB) run the independent layer-1 GEMM h1 = x @ W1^T (+ asd epilogue).
// attr loads are NONTEMPORAL (L3 no-allocate): A/B probe of the L3-service-path theory.
__global__ __launch_bounds__(256) void k_fused0(const float* __restrict__ attr,
                                                const int* __restrict__ col,
                                                const float* __restrict__ small,
                                                float* __restrict__ a_e1, float* __restrict__ a_e2,
                                                int* __restrict__ rank,
                                                int* __restrict__ counts,
                                                float* __restrict__ sums,
                                                unsigned* __restrict__ maxi,
                                                const float* __restrict__ x, const float* __restrict__ W1,
                                                float* __restrict__ h1,
                                                const float* __restrict__ as, const float* __restrict__ ad,
                                                float* __restrict__ asrc, float* __restrict__ adst) {
  __shared__ float smem[8704];   // edgepre: 8448 sattr + 16 redbuf | gemm: 2x 64x68 tiles
  int tid = threadIdx.x;
  if (blockIdx.x < EP_NB) {
    float* sattr = smem;
    float* redbuf = smem + 8448;
    float sp1[32], sp2[32];
    #pragma unroll
    for (int j = 0; j < 8; ++j) {
      float4 v1 = ((const float4*)(small + 128))[j];
      float4 v2 = ((const float4*)(small + 160))[j];
      sp1[j*4+0] = v1.x; sp1[j*4+1] = v1.y; sp1[j*4+2] = v1.z; sp1[j*4+3] = v1.w;
      sp2[j*4+0] = v2.x; sp2[j*4+1] = v2.y; sp2[j*4+2] = v2.z; sp2[j*4+3] = v2.w;
    }
    float c1 = small[192], c2 = small[193];
    int e = blockIdx.x * 256 + tid;
    int c = col[e];   // issue early
    const vfloat4* ain = (const vfloat4*)(attr + (size_t)blockIdx.x * 256 * FE);
    #pragma unroll
    for (int it = 0; it < 8; ++it) {
      int idx = it * 256 + tid;
      vfloat4 v = __builtin_nontemporal_load(ain + idx);
      int r = idx >> 3, ch = idx & 7;
      float* dst = &sattr[r * 33 + ch * 4];
      dst[0] = v.x; dst[1] = v.y; dst[2] = v.z; dst[3] = v.w;
    }
    __syncthreads();
    const float* myrow = &sattr[tid * 33];
    float d1 = c1, d2 = c2;
    #pragma unroll
    for (int j = 0; j < 32; ++j) {
      float a = myrow[j];
      d1 += a * sp1[j];
      d2 += a * sp2[j];
    }
    a_e1[e] = d1;
    a_e2[e] = d2;
    rank[e] = atomicAdd(&counts[c], 1);
    float s1 = d1, s2 = d2, m1 = d1, m2 = d2;
    #pragma unroll
    for (int m = 32; m; m >>= 1) {
      s1 += __shfl_xor(s1, m); s2 += __shfl_xor(s2, m);
      m1 = fmaxf(m1, __shfl_xor(m1, m)); m2 = fmaxf(m2, __shfl_xor(m2, m));
    }
    int wid = tid >> 6;
    if ((tid & 63) == 0) { redbuf[wid] = s1; redbuf[4 + wid] = s2; redbuf[8 + wid] = m1; redbuf[12 + wid] = m2; }
    __syncthreads();
    if (tid == 0) atomicAdd(&sums[0], redbuf[0] + redbuf[1] + redbuf[2] + redbuf[3]);
    if (tid == 1) atomicAdd(&sums[1], redbuf[4] + redbuf[5] + redbuf[6] + redbuf[7]);
    if (tid == 2) atomicMax(&maxi[2], omap(fmaxf(fmaxf(redbuf[8], redbuf[9]), fmaxf(redbuf[10], redbuf[11]))));
    if (tid == 3) atomicMax(&maxi[3], omap(fmaxf(fmaxf(redbuf[12], redbuf[13]), fmaxf(redbuf[14], redbuf[15]))));
  } else {
    // layer-1 GEMM: h1[NN][64] = x[NN][128] @ W1[64][128]^T, asd epilogue -> asrc/adst/maxi[0]
    float (*At)[68] = (float(*)[68])smem;
    float (*Bt)[68] = (float(*)[68])(smem + 4352);
    int m0 = (blockIdx.x - EP_NB) * 64;
    float acc[4][4] = {};
    for (int kc = 0; kc < 128; kc += 64) {
      #pragma unroll
      for (int it = 0; it < 4; ++it) {
        int idx = it * 256 + tid;
        int m = idx & 63, kv = idx >> 6;
        float4 bv = ((const float4*)(W1 + (size_t)m * 128 + kc))[kv];
        Bt[kv*4+0][m] = bv.x; Bt[kv*4+1][m] = bv.y; Bt[kv*4+2][m] = bv.z; Bt[kv*4+3][m] = bv.w;
        int gm = m0 + m;
        float4 av = make_float4(0.f, 0.f, 0.f, 0.f);
        if (gm < NN) av = ((const float4*)(x + (size_t)gm * 128 + kc))[kv];
        At[kv*4+0][m] = av.x; At[kv*4+1][m] = av.y; At[kv*4+2][m] = av.z; At[kv*4+3][m] = av.w;
      }
      __syncthreads();
      int tn = tid & 15, tm = tid >> 4;
      #pragma unroll 8
      for (int k = 0; k < 64; ++k) {
        float4 a4 = *(const float4*)&At[k][tm * 4];
        float4 b4 = *(const float4*)&Bt[k][tn * 4];
        acc[0][0] += a4.x*b4.x; acc[0][1] += a4.x*b4.y; acc[0][2] += a4.x*b4.z; acc[0][3] += a4.x*b4.w;
        acc[1][0] += a4.y*b4.x; acc[1][1] += a4.y*b4.y; acc[1][2] += a4.y*b4.z; acc[1][3] += a4.y*b4.w;
        acc[2][0] += a4.z*b4.x; acc[2][1] += a4.z*b4.y; acc[2][2] += a4.z*b4.z; acc[2][3] += a4.z*b4.w;
        acc[3][0] += a4.w*b4.x; acc[3][1] += a4.w*b4.y; acc[3][2] += a4.w*b4.z; acc[3][3] += a4.w*b4.w;
      }
      __syncthreads();
    }
    int tn = tid & 15, tm = tid >> 4;
    #pragma unroll
    for (int i = 0; i < 4; ++i) {
      int gm = m0 + tm * 4 + i;
      if (gm < NN) {
        float4 o = make_float4(acc[i][0], acc[i][1], acc[i][2], acc[i][3]);
        *(float4*)(h1 + (size_t)gm * 64 + tn * 4) = o;
      }
    }
    __shared__ float wmax[4];
    float4 asv = ((const float4*)as)[tn];
    float4 adv = ((const float4*)ad)[tn];
    float smax = -1e30f;
    #pragma unroll
    for (int i = 0; i < 4; ++i) {
      float s = acc[i][0]*asv.x + acc[i][1]*asv.y + acc[i][2]*asv.z + acc[i][3]*asv.w;
      float d = acc[i][0]*adv.x + acc[i][1]*adv.y + acc[i][2]*adv.z + acc[i][3]*adv.w;
      #pragma unroll
      for (int m = 8; m; m >>= 1) { s += __shfl_xor(s, m, 16); d += __shfl_xor(d, m, 16); }
      int gm = m0 + tm * 4 + i;
      if (tn == 0 && gm < NN) { asrc[gm] = s; adst[gm] = d; smax = fmaxf(smax, s); }
    }
    #pragma unroll
    for (int m = 32; m; m >>= 1) smax = fmaxf(smax, __shfl_xor(smax, m));
    if ((tid & 63) == 0) wmax[tid >> 6] = smax;
    __syncthreads();
    if (tid == 0)
      atomicMax(&maxi[0], omap(fmaxf(fmaxf(wmax[0], wmax[1]), fmaxf(wmax[2], wmax[3]))));
  }
}

// atomic-free scatter, 4 independent edge-chains per thread (MLP), guarded tail.
// pk[p] = {src, ae1_bits, ae2_bits, eid} — eid enables CSR-order k_final.
__global__ __launch_bounds__(256) void k_scatter(const int* __restrict__ row, const int* __restrict__ col,
                                                 const float* __restrict__ a_e1, const float* __restrict__ a_e2,
                                                 const int* __restrict__ rank, const int* __restrict__ offa,
                                                 int4* __restrict__ pk) {
  int t = blockIdx.x * 256 + threadIdx.x;
  if (t >= NE / 4) return;
  int e0 = t, e1 = t + NE / 4, e2 = t + NE / 2, e3 = t + 3 * (NE / 4);
  int c0 = col[e0], c1 = col[e1], c2 = col[e2], c3 = col[e3];
  int r0 = rank[e0], r1 = rank[e1], r2 = rank[e2], r3 = rank[e3];
  int o0 = offa[c0], o1 = offa[c1], o2 = offa[c2], o3 = offa[c3];
  int4 q0, q1, q2, q3;
  q0.x = row[e0]; q0.y = __float_as_int(a_e1[e0]); q0.z = __float_as_int(a_e2[e0]); q0.w = e0;
  q1.x = row[e1]; q1.y = __float_as_int(a_e1[e1]); q1.z = __float_as_int(a_e2[e1]); q1.w = e1;
  q2.x = row[e2]; q2.y = __float_as_int(a_e1[e2]); q2.z = __float_as_int(a_e2[e2]); q2.w = e2;
  q3.x = row[e3]; q3.y = __float_as_int(a_e1[e3]); q3.z = __float_as_int(a_e2[e3]); q3.w = e3;
  pk[o0 + r0] = q0;
  pk[o1 + r1] = q1;
  pk[o2 + r2] = q2;
  pk[o3 + r3] = q3;
}

// C[M][ldc-tile] = A[M][K] * B^T, B is [64][K] row-major (per blockIdx.y tile)
// ASD: also emit asrc/adst from the accumulator tile + global max(asrc) -> maxslot
template <int K, int ASD>
__global__ __launch_bounds__(256) void k_gemm(const float* __restrict__ A, const float* __restrict__ B,
                                              float* __restrict__ C, int M, int ldc,
                                              const float* __restrict__ as, const float* __restrict__ ad,
                                              float* __restrict__ asrc, float* __restrict__ adst,
                                              unsigned* __restrict__ maxslot) {
  __shared__ float At[64][68];
  __shared__ float Bt[64][68];
  int tid = threadIdx.x;
  int m0 = blockIdx.x * 64;
  const float* Bp = B + (size_t)blockIdx.y * 64 * K;
  float acc[4][4] = {};
  for (int kc = 0; kc < K; kc += 64) {
    #pragma unroll
    for (int it = 0; it < 4; ++it) {
      int idx = it * 256 + tid;
      int m = idx & 63, kv = idx >> 6;  // kv in 0..15
      float4 bv = ((const float4*)(Bp + (size_t)m * K + kc))[kv];
      Bt[kv*4+0][m] = bv.x; Bt[kv*4+1][m] = bv.y; Bt[kv*4+2][m] = bv.z; Bt[kv*4+3][m] = bv.w;
      int gm = m0 + m;
      float4 av = make_float4(0.f, 0.f, 0.f, 0.f);
      if (gm < M) av = ((const float4*)(A + (size_t)gm * K + kc))[kv];
      At[kv*4+0][m] = av.x; At[kv*4+1][m] = av.y; At[kv*4+2][m] = av.z; At[kv*4+3][m] = av.w;
    }
    __syncthreads();
    int tn = tid & 15, tm = tid >> 4;
    #pragma unroll 8
    for (int k = 0; k < 64; ++k) {
      float4 a4 = *(const float4*)&At[k][tm * 4];
      float4 b4 = *(const float4*)&Bt[k][tn * 4];
      acc[0][0] += a4.x*b4.x; acc[0][1] += a4.x*b4.y; acc[0][2] += a4.x*b4.z; acc[0][3] += a4.x*b4.w;
      acc[1][0] += a4.y*b4.x; acc[1][1] += a4.y*b4.y; acc[1][2] += a4.y*b4.z; acc[1][3] += a4.y*b4.w;
      acc[2][0] += a4.z*b4.x; acc[2][1] += a4.z*b4.y; acc[2][2] += a4.z*b4.z; acc[2][3] += a4.z*b4.w;
      acc[3][0] += a4.w*b4.x; acc[3][1] += a4.w*b4.y; acc[3][2] += a4.w*b4.z; acc[3][3] += a4.w*b4.w;
    }
    __syncthreads();
  }
  int tn = tid & 15, tm = tid >> 4;
  #pragma unroll
  for (int i = 0; i < 4; ++i) {
    int gm = m0 + tm * 4 + i;
    if (gm < M) {
      float4 o = make_float4(acc[i][0], acc[i][1], acc[i][2], acc[i][3]);
      *(float4*)(C + (size_t)gm * ldc + blockIdx.y * 64 + tn * 4) = o;
    }
  }
  if constexpr (ASD) {
    __shared__ float wmax[4];
    float4 asv = ((const float4*)as)[tn];
    float4 adv = ((const float4*)ad)[tn];
    float smax = -1e30f;
    #pragma unroll
    for (int i = 0; i < 4; ++i) {
      float s = acc[i][0]*asv.x + acc[i][1]*asv.y + acc[i][2]*asv.z + acc[i][3]*asv.w;
      float d = acc[i][0]*adv.x + acc[i][1]*adv.y + acc[i][2]*adv.z + acc[i][3]*adv.w;
      #pragma unroll
      for (int m = 8; m; m >>= 1) { s += __shfl_xor(s, m, 16); d += __shfl_xor(d, m, 16); }
      int gm = m0 + tm * 4 + i;
      if (tn == 0 && gm < M) { asrc[gm] = s; adst[gm] = d; smax = fmaxf(smax, s); }
    }
    #pragma unroll
    for (int m = 32; m; m >>= 1) smax = fmaxf(smax, __shfl_xor(smax, m));
    if ((tid & 63) == 0) wmax[tid >> 6] = smax;
    __syncthreads();
    if (tid == 0)
      atomicMax(maxslot, omap(fmaxf(fmaxf(wmax[0], wmax[1]), fmaxf(wmax[2], wmax[3]))));
  }
}

// one wave per destination node, SINGLE PASS softmax (global-bound shift),
// 8-way unrolled gather loop with independent accumulators (MLP for load latency).
__global__ __launch_bounds__(256) void k_agg(const float* __restrict__ h, const int* __restrict__ offa,
                                             const int4* __restrict__ pk, int comp,
                                             const float* __restrict__ asrc, const float* __restrict__ adst,
                                             const float* __restrict__ small, int selfIdx,
                                             const unsigned* __restrict__ maxi,
                                             const float* __restrict__ bias, float* __restrict__ outp,
                                             int do_relu) {
  int gt = blockIdx.x * 256 + threadIdx.x;
  int n = gt >> 6, lane = gt & 63;
  if (n >= NN) return;
  int beg = offa[n], end = offa[n + 1];
  float adn = adst[n];
  // shift bound: m >= every alpha in this segment (softmax is shift-invariant)
  float mx = lrelu(odec(maxi[comp]) + adn + odec(maxi[2 + comp]));
  float alpha_self = lrelu(asrc[n] + adn + small[selfIdx]);
  float ex_self = __expf(alpha_self - mx);
  float denom = ex_self;
  float acc0 = ex_self * h[(size_t)n * 64 + lane];
  float acc1 = 0.f, acc2 = 0.f, acc3 = 0.f;
  float acc4 = 0.f, acc5 = 0.f, acc6 = 0.f, acc7 = 0.f;
  for (int base = beg; base < end; base += 64) {
    int p = base + lane;
    int cnt = min(64, end - base);
    float ex = 0.f; int s = 0;
    if (p < end) {
      int4 q = pk[p];
      s = q.x;
      float ae = __int_as_float(comp ? q.z : q.y);
      ex = __expf(lrelu(asrc[s] + adn + ae) - mx);
    }
    float exs = ex;
    #pragma unroll
    for (int m = 32; m; m >>= 1) exs += __shfl_xor(exs, m);
    denom += exs;
    int q8 = cnt & ~7;
    int q = 0;
    for (; q < q8; q += 8) {
      float e0 = __shfl(ex, q),     e1 = __shfl(ex, q + 1);
      float e2 = __shfl(ex, q + 2), e3 = __shfl(ex, q + 3);
      float e4 = __shfl(ex, q + 4), e5 = __shfl(ex, q + 5);
      float e6 = __shfl(ex, q + 6), e7 = __shfl(ex, q + 7);
      int s0 = __shfl(s, q),     s1 = __shfl(s, q + 1);
      int s2 = __shfl(s, q + 2), s3 = __shfl(s, q + 3);
      int s4 = __shfl(s, q + 4), s5 = __shfl(s, q + 5);
      int s6 = __shfl(s, q + 6), s7 = __shfl(s, q + 7);
      acc0 += e0 * h[(size_t)s0 * 64 + lane];
      acc1 += e1 * h[(size_t)s1 * 64 + lane];
      acc2 += e2 * h[(size_t)s2 * 64 + lane];
      acc3 += e3 * h[(size_t)s3 * 64 + lane];
      acc4 += e4 * h[(size_t)s4 * 64 + lane];
      acc5 += e5 * h[(size_t)s5 * 64 + lane];
      acc6 += e6 * h[(size_t)s6 * 64 + lane];
      acc7 += e7 * h[(size_t)s7 * 64 + lane];
    }
    int q4 = cnt & ~3;
    if (q < q4) {
      float e0 = __shfl(ex, q),     e1 = __shfl(ex, q + 1);
      float e2 = __shfl(ex, q + 2), e3 = __shfl(ex, q + 3);
      int s0 = __shfl(s, q),     s1 = __shfl(s, q + 1);
      int s2 = __shfl(s, q + 2), s3 = __shfl(s, q + 3);
      acc0 += e0 * h[(size_t)s0 * 64 + lane];
      acc1 += e1 * h[(size_t)s1 * 64 + lane];
      acc2 += e2 * h[(size_t)s2 * 64 + lane];
      acc3 += e3 * h[(size_t)s3 * 64 + lane];
      q = q4;
    }
    for (; q < cnt; ++q) {
      float eq = __shfl(ex, q);
      int sq = __shfl(s, q);
      acc0 += eq * h[(size_t)sq * 64 + lane];
    }
  }
  float r = ((acc0 + acc1) + (acc2 + acc3)) + ((acc4 + acc5) + (acc6 + acc7));
  r = r / denom + bias[lane];
  if (do_relu) r = fmaxf(r, 0.f);
  outp[(size_t)n * 64 + lane] = r;
}

// edge scorer in CSR order: one wave per destination node; the v-half (uv[n][64..127])
// is loaded ONCE per node instead of per edge; only the u-gather stays random.
// 4x 16-lane groups each walk the segment stride-4, 2-way unrolled for MLP.
__global__ __launch_bounds__(256) void k_final(const int* __restrict__ offa, const int4* __restrict__ pk,
                                               const float* __restrict__ uv, const float* __restrict__ s1b,
                                               const float* __restrict__ s2w, const float* __restrict__ s2b,
                                               float* __restrict__ outp) {
  int gt = blockIdx.x * 256 + threadIdx.x;
  int n = gt >> 6, lane = gt & 63;
  if (n >= NN) return;
  int g = lane >> 4, i = lane & 15;
  int beg = offa[n], end = offa[n + 1];
  float4 v4 = ((const float4*)(uv + (size_t)n * 128 + 64))[i];
  float4 bb = ((const float4*)s1b)[i];
  float4 ww = ((const float4*)s2w)[i];
  float4 vb = make_float4(v4.x + bb.x, v4.y + bb.y, v4.z + bb.z, v4.w + bb.w);
  float sb = s2b[0];
  int p = beg + g;
  for (; p + 4 < end; p += 8) {
    int4 qa = pk[p];
    int4 qb = pk[p + 4];
    float4 ua = ((const float4*)(uv + (size_t)qa.x * 128))[i];
    float4 ub = ((const float4*)(uv + (size_t)qb.x * 128))[i];
    float za = fmaxf(ua.x + vb.x, 0.f) * ww.x + fmaxf(ua.y + vb.y, 0.f) * ww.y
             + fmaxf(ua.z + vb.z, 0.f) * ww.z + fmaxf(ua.w + vb.w, 0.f) * ww.w;
    float zb = fmaxf(ub.x + vb.x, 0.f) * ww.x + fmaxf(ub.y + vb.y, 0.f) * ww.y
             + fmaxf(ub.z + vb.z, 0.f) * ww.z + fmaxf(ub.w + vb.w, 0.f) * ww.w;
    #pragma unroll
    for (int m = 1; m < 16; m <<= 1) { za += __shfl_xor(za, m, 16); zb += __shfl_xor(zb, m, 16); }
    if (i == 0) {
      outp[qa.w] = 1.f / (1.f + __expf(-(za + sb)));
      outp[qb.w] = 1.f / (1.f + __expf(-(zb + sb)));
    }
  }
  if (p < end) {
    int4 q = pk[p];
    float4 u = ((const float4*)(uv + (size_t)q.x * 128))[i];
    float z = fmaxf(u.x + vb.x, 0.f) * ww.x + fmaxf(u.y + vb.y, 0.f) * ww.y
            + fmaxf(u.z + vb.z, 0.f) * ww.z + fmaxf(u.w + vb.w, 0.f) * ww.w;
    #pragma unroll
    for (int m = 1; m < 16; m <<= 1) z += __shfl_xor(z, m, 16);
    if (i == 0) outp[q.w] = 1.f / (1.f + __expf(-(z + sb)));
  }
}

extern "C" void kernel_launch(void* const* d_in, const int* in_sizes, int n_in,
                              void* d_out, int out_size, void* d_ws, size_t ws_size,
                              hipStream_t stream) {
  const float* x    = (const float*)d_in[0];
  const float* attr = (const float*)d_in[1];
  const int*   eidx = (const int*)d_in[2];   // [2][NE]: row then col
  const float* encW = (const float*)d_in[3];
  const float* encb = (const float*)d_in[4];
  const float* W1   = (const float*)d_in[5];
  const float* le1W = (const float*)d_in[6];
  const float* as1  = (const float*)d_in[7];
  const float* ad1  = (const float*)d_in[8];
  const float* ae1w = (const float*)d_in[9];
  const float* b1   = (const float*)d_in[10];
  const float* W2   = (const float*)d_in[11];
  const float* le2W = (const float*)d_in[12];
  const float* as2  = (const float*)d_in[13];
  const float* ad2  = (const float*)d_in[14];
  const float* ae2w = (const float*)d_in[15];
  const float* b2   = (const float*)d_in[16];
  const float* s1W  = (const float*)d_in[17];
  const float* s1b  = (const float*)d_in[18];
  const float* s2w  = (const float*)d_in[19];
  const float* s2b  = (const float*)d_in[20];
  float* outp = (float*)d_out;

  const int* row = eidx;
  const int* col = eidx + NE;

  char* p = (char*)d_ws;
  auto alloc = [&](size_t bytes) { char* r = p; p += (bytes + 255) & ~(size_t)255; return r; };
  float* small = (float*)alloc(1024);
  unsigned* maxi = (unsigned*)alloc(256);
  float* Scomb = (float*)alloc(8192 * 4);
  int*   counts= (int*)alloc((size_t)NN * 4);
  int*   offa  = (int*)alloc((size_t)(NN + 1) * 4);
  int*   bsums = (int*)alloc((size_t)SCAN_NB * 4);
  float* a_e1  = (float*)alloc((size_t)NE * 4);
  float* a_e2  = (float*)alloc((size_t)NE * 4);
  int*   rank  = (int*)alloc((size_t)NE * 4);
  int4*  pk    = (int4*)alloc((size_t)NE * 16);
  float* h1    = (float*)alloc((size_t)NN * 64 * 4);
  float* out1  = (float*)alloc((size_t)NN * 64 * 4);   // contiguous after h1
  float* h2    = (float*)alloc((size_t)NN * 64 * 4);
  float* out2  = (float*)alloc((size_t)NN * 64 * 4);
  float* asrc1 = (float*)alloc((size_t)NN * 4);
  float* adst1 = (float*)alloc((size_t)NN * 4);
  float* asrc2 = (float*)alloc((size_t)NN * 4);
  float* adst2 = (float*)alloc((size_t)NN * 4);
  float* uv = h1;  // [NN][128], reuses h1||out1 (both dead by then)

  // small (1024B) and maxi (256B) are adjacent in d_ws: one memset covers both
  hipMemsetAsync(small, 0, 1280, stream);

  // block 0: small-param precompute; blocks 1..196: zero counts
  k_small0<<<SCAN_NB + 1, 256, 0, stream>>>(le1W, ae1w, le2W, ae2w, encW, encb, s1W, small, Scomb, counts);
  // fused: edgepre (3125 blocks, nt attr loads) + layer-1 GEMM (782 blocks)
  k_fused0<<<EP_NB + GM_NB, 256, 0, stream>>>(attr, col, small, a_e1, a_e2, rank, counts,
                                              small + 228, maxi, x, W1, h1, as1, ad1, asrc1, adst1);
  k_scanA<<<SCAN_NB, 256, 0, stream>>>(counts, offa, bsums);
  k_scanBC<<<SCAN_NB, 256, 0, stream>>>(bsums, offa, small);
  k_scatter<<<(NE / 4 + 255) / 256, 256, 0, stream>>>(row, col, a_e1, a_e2, rank, offa, pk);

  // layer 1 aggregation
  k_agg<<<(NN * 64) / 256, 256, 0, stream>>>(h1, offa, pk, 0, asrc1, adst1,
                                             small, 194, maxi, b1, out1, 1);
  // layer 2
  k_gemm<64, 1><<<dim3((NN + 63) / 64, 1), 256, 0, stream>>>(out1, W2, h2, NN, 64, as2, ad2, asrc2, adst2, maxi + 1);
  k_agg<<<(NN * 64) / 256, 256, 0, stream>>>(h2, offa, pk, 1, asrc2, adst2,
                                             small, 195, maxi, b2, out2, 0);
  // scorer: uv = [u | v]
  k_gemm<64, 0><<<dim3((NN + 63) / 64, 2), 256, 0, stream>>>(out2, Scomb, uv, NN, 128, nullptr, nullptr, nullptr, nullptr, nullptr);
  k_final<<<(NN * 64) / 256, 256, 0, stream>>>(offa, pk, uv, s1b, s2w, s2b, outp);
}